// Round 1
// baseline (2337.789 us; speedup 1.0000x reference)
//
#include <hip/hip_runtime.h>
#include <math.h>

#define B_TOT 512
#define SEQ   179
#define EMB   256
#define HEADS 8
#define HD    32
#define LIN   720
#define EPSV  1e-5f

// ---------------------------------------------------------------- PE table
__global__ void pe_kernel(float* __restrict__ pe) {
    int idx = blockIdx.x * 256 + threadIdx.x;
    if (idx >= SEQ * EMB) return;
    int s = idx / EMB, e = idx % EMB;
    int i = e >> 1;
    float dv  = expf((float)(2 * i) * (-9.210340371976184f / (float)EMB)); // -ln(10000)/EMB
    float ang = (float)s * dv * ((float)EMB / (float)SEQ);
    pe[idx] = (e & 1) ? cosf(ang) : sinf(ang);
}

// ------------------------------------- conv(stride4,K8) + BN + ReLU + PE
__global__ __launch_bounds__(256) void embed_kernel(
    const float* __restrict__ x, const float* __restrict__ cw,
    const float* __restrict__ cb, const float* __restrict__ g,
    const float* __restrict__ bb, const float* __restrict__ mean,
    const float* __restrict__ var, const float* __restrict__ pe,
    float* __restrict__ X)
{
    int bs = blockIdx.x;              // b * SEQ + s  (b within chunk)
    int b  = bs / SEQ, s = bs % SEQ;
    int e  = threadIdx.x;
    __shared__ float xin[8];
    if (threadIdx.x < 8) xin[threadIdx.x] = x[(size_t)b * LIN + s * 4 + threadIdx.x];
    __syncthreads();
    float acc = cb[e];
#pragma unroll
    for (int j = 0; j < 8; ++j) acc += xin[j] * cw[e * 8 + j];
    acc = (acc - mean[e]) * (g[e] * rsqrtf(var[e] + EPSV)) + bb[e];
    acc = fmaxf(acc, 0.f);
    X[(size_t)bs * EMB + e] = acc + pe[s * EMB + e];
}

// --------------------------- tiled f32 GEMM: C = A[M,256] * W[256,256]^T
// blockIdx.y in [0,12): selects {wq,wk,wv} and 64-col strip.
__global__ __launch_bounds__(256) void gemm_qkv(
    const float* __restrict__ A,
    const float* __restrict__ wq, const float* __restrict__ wk,
    const float* __restrict__ wv,
    float* __restrict__ Q, float* __restrict__ Kc, float* __restrict__ V,
    int M)
{
    int by = blockIdx.y;
    const float* W = (by < 4) ? wq : (by < 8 ? wk : wv);
    float* C       = (by < 4) ? Q  : (by < 8 ? Kc : V);
    int nbase = (by & 3) * 64;
    int mbase = blockIdx.x * 64;

    __shared__ float As[16][64];
    __shared__ float Ws[16][64];

    int tid  = threadIdx.x;
    int tm   = tid >> 4;          // 0..15  -> rows tm*4..tm*4+3
    int tn   = tid & 15;          // 0..15  -> cols tn*4..tn*4+3
    int lrow = tid >> 2;          // 0..63
    int lk4  = (tid & 3) * 4;     // 0,4,8,12

    float acc[4][4];
#pragma unroll
    for (int i = 0; i < 4; ++i)
#pragma unroll
        for (int j = 0; j < 4; ++j) acc[i][j] = 0.f;

    for (int kt = 0; kt < EMB; kt += 16) {
        int m = mbase + lrow;
        float4 av = make_float4(0.f, 0.f, 0.f, 0.f);
        if (m < M) av = *reinterpret_cast<const float4*>(&A[(size_t)m * EMB + kt + lk4]);
        As[lk4 + 0][lrow] = av.x; As[lk4 + 1][lrow] = av.y;
        As[lk4 + 2][lrow] = av.z; As[lk4 + 3][lrow] = av.w;

        float4 wv4 = *reinterpret_cast<const float4*>(&W[(size_t)(nbase + lrow) * EMB + kt + lk4]);
        Ws[lk4 + 0][lrow] = wv4.x; Ws[lk4 + 1][lrow] = wv4.y;
        Ws[lk4 + 2][lrow] = wv4.z; Ws[lk4 + 3][lrow] = wv4.w;
        __syncthreads();

#pragma unroll
        for (int k = 0; k < 16; ++k) {
            float a[4], bv[4];
#pragma unroll
            for (int i = 0; i < 4; ++i) a[i]  = As[k][tm * 4 + i];
#pragma unroll
            for (int j = 0; j < 4; ++j) bv[j] = Ws[k][tn * 4 + j];
#pragma unroll
            for (int i = 0; i < 4; ++i)
#pragma unroll
                for (int j = 0; j < 4; ++j) acc[i][j] += a[i] * bv[j];
        }
        __syncthreads();
    }

#pragma unroll
    for (int i = 0; i < 4; ++i) {
        int m = mbase + tm * 4 + i;
        if (m < M)
            *reinterpret_cast<float4*>(&C[(size_t)m * EMB + nbase + tn * 4]) =
                make_float4(acc[i][0], acc[i][1], acc[i][2], acc[i][3]);
    }
}

// ---------------- per-(b,h) attention, online softmax, K/V staged in LDS
__global__ __launch_bounds__(256) void attn_kernel(
    const float* __restrict__ Q, const float* __restrict__ K,
    const float* __restrict__ V, float* __restrict__ O)
{
    int bh = blockIdx.x;
    int b = bh >> 3, h = bh & 7;
    __shared__ float ks[SEQ][HD];
    __shared__ float vs[SEQ][HD];
    int tid = threadIdx.x;
    const size_t base = (size_t)b * SEQ * EMB + h * HD;

    for (int idx = tid; idx < SEQ * HD; idx += 256) {
        int t = idx >> 5, d = idx & 31;
        ks[t][d] = K[base + (size_t)t * EMB + d];
        vs[t][d] = V[base + (size_t)t * EMB + d];
    }
    __syncthreads();

    int s = tid;
    if (s < SEQ) {
        float q[HD];
#pragma unroll
        for (int d = 0; d < HD; ++d) q[d] = Q[base + (size_t)s * EMB + d];
        float m = -1e30f, l = 0.f;
        float acc[HD];
#pragma unroll
        for (int d = 0; d < HD; ++d) acc[d] = 0.f;
        const float scale = 0.0625f;           // EMB^-0.5 = 1/16
        const float invS  = 1.0f / (float)SEQ;

        for (int t = 0; t < SEQ; ++t) {
            float dot = 0.f;
#pragma unroll
            for (int d = 0; d < HD; ++d) dot += q[d] * ks[t][d];
            float swv   = fabsf((float)(s - t)) * invS;
            float logit = dot * scale * swv;
            float mNew  = fmaxf(m, logit);
            float corr  = expf(m - mNew);
            float p     = expf(logit - mNew);
            l = l * corr + p;
#pragma unroll
            for (int d = 0; d < HD; ++d) acc[d] = acc[d] * corr + p * vs[t][d];
            m = mNew;
        }
        float inv_l = 1.0f / l;
        float* op = &O[base + (size_t)s * EMB];
#pragma unroll
        for (int dd = 0; dd < 8; ++dd)
            *reinterpret_cast<float4*>(&op[dd * 4]) =
                make_float4(acc[dd*4] * inv_l, acc[dd*4+1] * inv_l,
                            acc[dd*4+2] * inv_l, acc[dd*4+3] * inv_l);
    }
}

// ----------------------------- row LayerNorm (in-place), optional +PE
__global__ __launch_bounds__(256) void ln_kernel(
    float* __restrict__ X, const float* __restrict__ g,
    const float* __restrict__ bb, const float* __restrict__ pe, int add_pe)
{
    int bs = blockIdx.x;
    int s  = bs % SEQ;
    int e  = threadIdx.x;
    float v = X[(size_t)bs * EMB + e];

    float sum = v, sumsq = v * v;
#pragma unroll
    for (int off = 32; off > 0; off >>= 1) {
        sum   += __shfl_down(sum, off);
        sumsq += __shfl_down(sumsq, off);
    }
    __shared__ float ps[4], pss[4];
    int wave = e >> 6, lane = e & 63;
    if (lane == 0) { ps[wave] = sum; pss[wave] = sumsq; }
    __syncthreads();
    float tot   = ps[0] + ps[1] + ps[2] + ps[3];
    float totsq = pss[0] + pss[1] + pss[2] + pss[3];
    float mu  = tot * (1.0f / EMB);
    float var = totsq * (1.0f / EMB) - mu * mu;

    float y = (v - mu) * rsqrtf(var + EPSV) * g[e] + bb[e];
    if (add_pe) y += pe[s * EMB + e];
    X[(size_t)bs * EMB + e] = y;
}

// --------------------------------- mean-pool over SEQ + final FC [10]
__global__ __launch_bounds__(256) void final_kernel(
    const float* __restrict__ X, const float* __restrict__ ow,
    const float* __restrict__ ob, float* __restrict__ out)
{
    int b = blockIdx.x;
    int e = threadIdx.x;
    float acc = 0.f;
    for (int s = 0; s < SEQ; ++s) acc += X[((size_t)b * SEQ + s) * EMB + e];
    __shared__ float pooled[EMB];
    pooled[e] = acc * (1.0f / (float)SEQ);
    __syncthreads();
    if (e < 10) {
        float o = ob[e];
        for (int k = 0; k < EMB; ++k) o += pooled[k] * ow[e * EMB + k];
        out[b * 10 + e] = o;
    }
}

// ---------------------------------------------------------------- launch
extern "C" void kernel_launch(void* const* d_in, const int* in_sizes, int n_in,
                              void* d_out, int out_size, void* d_ws, size_t ws_size,
                              hipStream_t stream)
{
    const float* x      = (const float*)d_in[0];
    const float* conv_w = (const float*)d_in[1];
    const float* conv_b = (const float*)d_in[2];
    const float* bn_g   = (const float*)d_in[3];
    const float* bn_b   = (const float*)d_in[4];
    const float* bn_m   = (const float*)d_in[5];
    const float* bn_v   = (const float*)d_in[6];
    const float* wq1    = (const float*)d_in[7];
    const float* wk1    = (const float*)d_in[8];
    const float* wv1    = (const float*)d_in[9];
    const float* lnA1_g = (const float*)d_in[10];
    const float* lnA1_b = (const float*)d_in[11];
    const float* wq2    = (const float*)d_in[12];
    const float* wk2    = (const float*)d_in[13];
    const float* wv2    = (const float*)d_in[14];
    const float* lnA2_g = (const float*)d_in[15];
    const float* lnA2_b = (const float*)d_in[16];
    const float* ln2_g  = (const float*)d_in[17];
    const float* ln2_b  = (const float*)d_in[18];
    const float* out_w  = (const float*)d_in[19];
    const float* out_b  = (const float*)d_in[20];
    float* out = (float*)d_out;

    const size_t peN = (size_t)SEQ * EMB;

    // pick largest power-of-two batch chunk whose 4 buffers + PE fit in ws
    int chunk = B_TOT;
    while (chunk > 1) {
        size_t need = (peN + 4ull * (size_t)chunk * SEQ * EMB) * sizeof(float);
        if (need <= ws_size) break;
        chunk >>= 1;
    }

    float* pe = (float*)d_ws;
    float* X  = pe + peN;
    size_t bufN = (size_t)chunk * SEQ * EMB;
    float* Q = X + bufN;
    float* K = Q + bufN;
    float* V = K + bufN;

    pe_kernel<<<(SEQ * EMB + 255) / 256, 256, 0, stream>>>(pe);

    for (int b0 = 0; b0 < B_TOT; b0 += chunk) {
        int Bc = chunk;
        int M  = Bc * SEQ;
        dim3 ggrid((M + 63) / 64, 12);

        embed_kernel<<<Bc * SEQ, 256, 0, stream>>>(
            x + (size_t)b0 * LIN, conv_w, conv_b, bn_g, bn_b, bn_m, bn_v, pe, X);

        // --- attention block 1 ---
        gemm_qkv<<<ggrid, 256, 0, stream>>>(X, wq1, wk1, wv1, Q, K, V, M);
        attn_kernel<<<Bc * HEADS, 256, 0, stream>>>(Q, K, V, X);
        ln_kernel<<<Bc * SEQ, 256, 0, stream>>>(X, lnA1_g, lnA1_b, pe, 1);

        // --- attention block 2 ---
        gemm_qkv<<<ggrid, 256, 0, stream>>>(X, wq2, wk2, wv2, Q, K, V, M);
        attn_kernel<<<Bc * HEADS, 256, 0, stream>>>(Q, K, V, X);
        ln_kernel<<<Bc * SEQ, 256, 0, stream>>>(X, lnA2_g, lnA2_b, pe, 0);
        ln_kernel<<<Bc * SEQ, 256, 0, stream>>>(X, ln2_g, ln2_b, pe, 0);

        final_kernel<<<Bc, 256, 0, stream>>>(X, out_w, out_b, out + (size_t)b0 * 10);
    }
}

// Round 2
// 1442.926 us; speedup vs baseline: 1.6202x; 1.6202x over previous
//
#include <hip/hip_runtime.h>
#include <hip/hip_bf16.h>
#include <math.h>

#define B_TOT 512
#define SEQ   179
#define EMB   256
#define HEADS 8
#define HD    32
#define LIN   720
#define EPSV  1e-5f

typedef __attribute__((ext_vector_type(8))) short bf16x8;
typedef __attribute__((ext_vector_type(4))) float f32x4;

__device__ __forceinline__ float bf_lo(unsigned u) { return __uint_as_float(u << 16); }
__device__ __forceinline__ float bf_hi(unsigned u) { return __uint_as_float(u & 0xffff0000u); }

// ---------------------------------------------------------------- PE table
__global__ void pe_kernel(float* __restrict__ pe) {
    int idx = blockIdx.x * 256 + threadIdx.x;
    if (idx >= SEQ * EMB) return;
    int s = idx / EMB, e = idx % EMB;
    int i = e >> 1;
    float dv  = expf((float)(2 * i) * (-9.210340371976184f / (float)EMB));
    float ang = (float)s * dv * ((float)EMB / (float)SEQ);
    pe[idx] = (e & 1) ? cosf(ang) : sinf(ang);
}

// ----------------------------------------------------- f32 -> bf16 convert
__global__ void cvt_bf16_kernel(const float* __restrict__ src,
                                __hip_bfloat16* __restrict__ dst, int n) {
    int i = (blockIdx.x * 256 + threadIdx.x) * 4;
    if (i < n) {
        float4 v = *reinterpret_cast<const float4*>(&src[i]);
        dst[i + 0] = __float2bfloat16(v.x);
        dst[i + 1] = __float2bfloat16(v.y);
        dst[i + 2] = __float2bfloat16(v.z);
        dst[i + 3] = __float2bfloat16(v.w);
    }
}

// ------------------------ conv(stride4,K8) + BN + ReLU + PE -> bf16 X
__global__ __launch_bounds__(256) void embed_kernel(
    const float* __restrict__ x, const float* __restrict__ cw,
    const float* __restrict__ cb, const float* __restrict__ g,
    const float* __restrict__ bb, const float* __restrict__ mean,
    const float* __restrict__ var, const float* __restrict__ pe,
    __hip_bfloat16* __restrict__ Xb)
{
    int bs = blockIdx.x;
    int b  = bs / SEQ, s = bs % SEQ;
    int e  = threadIdx.x;
    __shared__ float xin[8];
    if (threadIdx.x < 8) xin[threadIdx.x] = x[(size_t)b * LIN + s * 4 + threadIdx.x];
    __syncthreads();
    float acc = cb[e];
#pragma unroll
    for (int j = 0; j < 8; ++j) acc += xin[j] * cw[e * 8 + j];
    acc = (acc - mean[e]) * (g[e] * rsqrtf(var[e] + EPSV)) + bb[e];
    acc = fmaxf(acc, 0.f);
    Xb[(size_t)bs * EMB + e] = __float2bfloat16(acc + pe[s * EMB + e]);
}

// ---------------- MFMA bf16 GEMM: C[m,n] = sum_k A[m,k] * W[n,k], C in bf16
// 128x128 tile, BK=64, 4 waves (2x2), each wave 64x64 (4x4 frags of 16x16x32)
// LDS XOR-swizzle (T2, rule #21): linear LDS dest for global_load_lds,
// inverse-swizzled GLOBAL source, swizzled ds_read.
__global__ __launch_bounds__(256) void gemm_qkv_mfma(
    const __hip_bfloat16* __restrict__ A,    // [Mpad][256]
    const __hip_bfloat16* __restrict__ Wset, // [3][256][256]
    __hip_bfloat16* __restrict__ Q, __hip_bfloat16* __restrict__ K,
    __hip_bfloat16* __restrict__ V, int M)
{
    int by = blockIdx.y;                       // 0..5
    int wsel = by >> 1;
    const __hip_bfloat16* W = Wset + (size_t)wsel * EMB * EMB;
    __hip_bfloat16* C = (wsel == 0) ? Q : (wsel == 1 ? K : V);
    int nbase = (by & 1) * 128;
    int mbase = blockIdx.x * 128;

    __shared__ __hip_bfloat16 As[128][64];
    __shared__ __hip_bfloat16 Bs[128][64];

    int tid  = threadIdx.x;
    int wave = tid >> 6, lane = tid & 63;
    int wr = wave >> 1, wc = wave & 1;

    // staging address precompute: thread covers LDS bytes i*4096 + tid*16
    int r0   = tid >> 3;                       // row within 32-row slab
    int srcs = (tid & 7) ^ (r0 & 7);           // inverse-swizzled source slot
    const __hip_bfloat16* gA = A + (size_t)(mbase + r0) * EMB + srcs * 8;
    const __hip_bfloat16* gB = W + (size_t)(nbase + r0) * EMB + srcs * 8;

    f32x4 acc[4][4];
#pragma unroll
    for (int i = 0; i < 4; ++i)
#pragma unroll
        for (int j = 0; j < 4; ++j) acc[i][j] = (f32x4){0.f, 0.f, 0.f, 0.f};

    for (int kt = 0; kt < EMB; kt += 64) {
        if (kt) __syncthreads();
#pragma unroll
        for (int i = 0; i < 4; ++i) {
            __hip_bfloat16* l = &As[0][0] + i * 2048 + tid * 8;
            __builtin_amdgcn_global_load_lds(
                (const __attribute__((address_space(1))) void*)(gA + (size_t)i * 32 * EMB + kt),
                (__attribute__((address_space(3))) void*)l, 16, 0, 0);
        }
#pragma unroll
        for (int i = 0; i < 4; ++i) {
            __hip_bfloat16* l = &Bs[0][0] + i * 2048 + tid * 8;
            __builtin_amdgcn_global_load_lds(
                (const __attribute__((address_space(1))) void*)(gB + (size_t)i * 32 * EMB + kt),
                (__attribute__((address_space(3))) void*)l, 16, 0, 0);
        }
        asm volatile("s_waitcnt vmcnt(0)" ::: "memory");
        __syncthreads();

#pragma unroll
        for (int kk = 0; kk < 2; ++kk) {
            bf16x8 af[4], bfr[4];
            int sg = kk * 4 + (lane >> 4);     // global 16B slot within row
#pragma unroll
            for (int mi = 0; mi < 4; ++mi) {
                int row = wr * 64 + mi * 16 + (lane & 15);
                int sl  = sg ^ (row & 7);
                af[mi] = *reinterpret_cast<const bf16x8*>(&As[row][sl * 8]);
            }
#pragma unroll
            for (int ni = 0; ni < 4; ++ni) {
                int row = wc * 64 + ni * 16 + (lane & 15);
                int sl  = sg ^ (row & 7);
                bfr[ni] = *reinterpret_cast<const bf16x8*>(&Bs[row][sl * 8]);
            }
#pragma unroll
            for (int mi = 0; mi < 4; ++mi)
#pragma unroll
                for (int ni = 0; ni < 4; ++ni)
                    acc[mi][ni] = __builtin_amdgcn_mfma_f32_16x16x32_bf16(
                        af[mi], bfr[ni], acc[mi][ni], 0, 0, 0);
        }
    }

    // C/D layout: col = lane&15, row = (lane>>4)*4 + j   [m89-verified]
    int rg = lane >> 4, cl = lane & 15;
#pragma unroll
    for (int mi = 0; mi < 4; ++mi)
#pragma unroll
        for (int j = 0; j < 4; ++j) {
            int m = mbase + wr * 64 + mi * 16 + rg * 4 + j;
            if (m < M) {
#pragma unroll
                for (int ni = 0; ni < 4; ++ni)
                    C[(size_t)m * EMB + nbase + wc * 64 + ni * 16 + cl] =
                        __float2bfloat16(acc[mi][ni][j]);
            }
        }
}

// ---------------- per-(b,h) attention, online softmax, K/V f32-staged in LDS
__global__ __launch_bounds__(256) void attn_kernel(
    const __hip_bfloat16* __restrict__ Qb, const __hip_bfloat16* __restrict__ Kb,
    const __hip_bfloat16* __restrict__ Vb, float* __restrict__ O)
{
    int bh = blockIdx.x;
    int b = bh >> 3, h = bh & 7;
    __shared__ float ks[SEQ][HD];
    __shared__ float vs[SEQ][HD];
    int tid = threadIdx.x;
    const size_t base = (size_t)b * SEQ * EMB + h * HD;

    for (int c = tid; c < (SEQ * HD) / 8; c += 256) {
        int t = c >> 2, d0 = (c & 3) << 3;
        size_t go = base + (size_t)t * EMB + d0;
        uint4 kr = *reinterpret_cast<const uint4*>(&Kb[go]);
        uint4 vr = *reinterpret_cast<const uint4*>(&Vb[go]);
        float* kd = &ks[t][d0];
        float* vd = &vs[t][d0];
        kd[0]=bf_lo(kr.x); kd[1]=bf_hi(kr.x); kd[2]=bf_lo(kr.y); kd[3]=bf_hi(kr.y);
        kd[4]=bf_lo(kr.z); kd[5]=bf_hi(kr.z); kd[6]=bf_lo(kr.w); kd[7]=bf_hi(kr.w);
        vd[0]=bf_lo(vr.x); vd[1]=bf_hi(vr.x); vd[2]=bf_lo(vr.y); vd[3]=bf_hi(vr.y);
        vd[4]=bf_lo(vr.z); vd[5]=bf_hi(vr.z); vd[6]=bf_lo(vr.w); vd[7]=bf_hi(vr.w);
    }
    __syncthreads();

    int s = tid;
    if (s < SEQ) {
        float q[HD];
        const uint4* qp = reinterpret_cast<const uint4*>(&Qb[base + (size_t)s * EMB]);
#pragma unroll
        for (int r = 0; r < 4; ++r) {
            uint4 raw = qp[r];
            q[r*8+0]=bf_lo(raw.x); q[r*8+1]=bf_hi(raw.x); q[r*8+2]=bf_lo(raw.y); q[r*8+3]=bf_hi(raw.y);
            q[r*8+4]=bf_lo(raw.z); q[r*8+5]=bf_hi(raw.z); q[r*8+6]=bf_lo(raw.w); q[r*8+7]=bf_hi(raw.w);
        }
        float m = -1e30f, l = 0.f;
        float acc[HD];
#pragma unroll
        for (int d = 0; d < HD; ++d) acc[d] = 0.f;
        const float scale = 0.0625f;
        const float invS  = 1.0f / (float)SEQ;

        for (int t = 0; t < SEQ; ++t) {
            float dot = 0.f;
#pragma unroll
            for (int d = 0; d < HD; ++d) dot += q[d] * ks[t][d];
            float swv   = fabsf((float)(s - t)) * invS;
            float logit = dot * scale * swv;
            float mNew  = fmaxf(m, logit);
            float corr  = expf(m - mNew);
            float p     = expf(logit - mNew);
            l = l * corr + p;
#pragma unroll
            for (int d = 0; d < HD; ++d) acc[d] = acc[d] * corr + p * vs[t][d];
            m = mNew;
        }
        float inv_l = 1.0f / l;
        float* op = &O[base + (size_t)s * EMB];
#pragma unroll
        for (int dd = 0; dd < 8; ++dd)
            *reinterpret_cast<float4*>(&op[dd * 4]) =
                make_float4(acc[dd*4] * inv_l, acc[dd*4+1] * inv_l,
                            acc[dd*4+2] * inv_l, acc[dd*4+3] * inv_l);
    }
}

// ---------------- row LayerNorm + PE, writes bf16 (feeds next GEMM)
__global__ __launch_bounds__(256) void ln_bf16_pe_kernel(
    const float* __restrict__ X, const float* __restrict__ g,
    const float* __restrict__ bb, const float* __restrict__ pe,
    __hip_bfloat16* __restrict__ Xb)
{
    int bs = blockIdx.x;
    int s  = bs % SEQ;
    int e  = threadIdx.x;
    float v = X[(size_t)bs * EMB + e];

    float sum = v, sumsq = v * v;
#pragma unroll
    for (int off = 32; off > 0; off >>= 1) {
        sum   += __shfl_down(sum, off);
        sumsq += __shfl_down(sumsq, off);
    }
    __shared__ float ps[4], pss[4];
    int wave = e >> 6, lane = e & 63;
    if (lane == 0) { ps[wave] = sum; pss[wave] = sumsq; }
    __syncthreads();
    float tot   = ps[0] + ps[1] + ps[2] + ps[3];
    float totsq = pss[0] + pss[1] + pss[2] + pss[3];
    float mu  = tot * (1.0f / EMB);
    float var = totsq * (1.0f / EMB) - mu * mu;
    float y = (v - mu) * rsqrtf(var + EPSV) * g[e] + bb[e] + pe[s * EMB + e];
    Xb[(size_t)bs * EMB + e] = __float2bfloat16(y);
}

// ---------------- fused double LayerNorm (lnA2 then ln2), f32 in-place
__global__ __launch_bounds__(256) void ln2x_kernel(
    float* __restrict__ X, const float* __restrict__ g1, const float* __restrict__ b1,
    const float* __restrict__ g2, const float* __restrict__ b2)
{
    int bs = blockIdx.x;
    int e  = threadIdx.x;
    int wave = e >> 6, lane = e & 63;
    __shared__ float ps[4], pss[4];

    float v = X[(size_t)bs * EMB + e];
    float sum = v, sumsq = v * v;
#pragma unroll
    for (int off = 32; off > 0; off >>= 1) {
        sum   += __shfl_down(sum, off);
        sumsq += __shfl_down(sumsq, off);
    }
    if (lane == 0) { ps[wave] = sum; pss[wave] = sumsq; }
    __syncthreads();
    float tot   = ps[0] + ps[1] + ps[2] + ps[3];
    float totsq = pss[0] + pss[1] + pss[2] + pss[3];
    float mu  = tot * (1.0f / EMB);
    float var = totsq * (1.0f / EMB) - mu * mu;
    float y1 = (v - mu) * rsqrtf(var + EPSV) * g1[e] + b1[e];
    __syncthreads();

    sum = y1; sumsq = y1 * y1;
#pragma unroll
    for (int off = 32; off > 0; off >>= 1) {
        sum   += __shfl_down(sum, off);
        sumsq += __shfl_down(sumsq, off);
    }
    if (lane == 0) { ps[wave] = sum; pss[wave] = sumsq; }
    __syncthreads();
    tot   = ps[0] + ps[1] + ps[2] + ps[3];
    totsq = pss[0] + pss[1] + pss[2] + pss[3];
    mu  = tot * (1.0f / EMB);
    var = totsq * (1.0f / EMB) - mu * mu;
    X[(size_t)bs * EMB + e] = (y1 - mu) * rsqrtf(var + EPSV) * g2[e] + b2[e];
}

// --------------------------------- mean-pool over SEQ + final FC [10]
__global__ __launch_bounds__(256) void final_kernel(
    const float* __restrict__ X, const float* __restrict__ ow,
    const float* __restrict__ ob, float* __restrict__ out)
{
    int b = blockIdx.x;
    int e = threadIdx.x;
    float acc = 0.f;
    for (int s = 0; s < SEQ; ++s) acc += X[((size_t)b * SEQ + s) * EMB + e];
    __shared__ float pooled[EMB];
    pooled[e] = acc * (1.0f / (float)SEQ);
    __syncthreads();
    if (e < 10) {
        float o = ob[e];
        for (int k = 0; k < EMB; ++k) o += pooled[k] * ow[e * EMB + k];
        out[b * 10 + e] = o;
    }
}

// ---------------------------------------------------------------- launch
extern "C" void kernel_launch(void* const* d_in, const int* in_sizes, int n_in,
                              void* d_out, int out_size, void* d_ws, size_t ws_size,
                              hipStream_t stream)
{
    const float* x      = (const float*)d_in[0];
    const float* conv_w = (const float*)d_in[1];
    const float* conv_b = (const float*)d_in[2];
    const float* bn_g   = (const float*)d_in[3];
    const float* bn_b   = (const float*)d_in[4];
    const float* bn_m   = (const float*)d_in[5];
    const float* bn_v   = (const float*)d_in[6];
    const float* wq1    = (const float*)d_in[7];
    const float* wk1    = (const float*)d_in[8];
    const float* wv1    = (const float*)d_in[9];
    const float* lnA1_g = (const float*)d_in[10];
    const float* lnA1_b = (const float*)d_in[11];
    const float* wq2    = (const float*)d_in[12];
    const float* wk2    = (const float*)d_in[13];
    const float* wv2    = (const float*)d_in[14];
    const float* lnA2_g = (const float*)d_in[15];
    const float* lnA2_b = (const float*)d_in[16];
    const float* ln2_g  = (const float*)d_in[17];
    const float* ln2_b  = (const float*)d_in[18];
    const float* out_w  = (const float*)d_in[19];
    const float* out_b  = (const float*)d_in[20];
    float* out = (float*)d_out;

    const size_t peN = (size_t)SEQ * EMB;         // 45824
    const size_t wN  = (size_t)EMB * EMB;         // 65536

    // pick largest power-of-two chunk that fits:
    // pe(f32) + Wb(6 x bf16) + Xb(bf16, Mpad) + X(f32, M) + Q/K/V(bf16, M)
    int chunk = B_TOT;
    while (chunk > 1) {
        size_t M    = (size_t)chunk * SEQ;
        size_t Mpad = (M + 127) / 128 * 128;
        size_t need = peN * 4 + 6 * wN * 2 + Mpad * EMB * 2
                    + M * EMB * 4 + 3 * M * EMB * 2;
        if (need <= ws_size) break;
        chunk >>= 1;
    }
    size_t M    = (size_t)chunk * SEQ;
    size_t Mpad = (M + 127) / 128 * 128;

    float*          pe = (float*)d_ws;
    __hip_bfloat16* Wb = (__hip_bfloat16*)(pe + peN);
    __hip_bfloat16* Xb = Wb + 6 * wN;
    float*          X  = (float*)(Xb + Mpad * EMB);
    __hip_bfloat16* Qb = (__hip_bfloat16*)(X + M * EMB);
    __hip_bfloat16* Kb = Qb + M * EMB;
    __hip_bfloat16* Vb = Kb + M * EMB;

    pe_kernel<<<(SEQ * EMB + 255) / 256, 256, 0, stream>>>(pe);

    const float* Wsrc[6] = {wq1, wk1, wv1, wq2, wk2, wv2};
    for (int w = 0; w < 6; ++w)
        cvt_bf16_kernel<<<(int)(wN / 1024), 256, 0, stream>>>(Wsrc[w], Wb + (size_t)w * wN, (int)wN);

    for (int b0 = 0; b0 < B_TOT; b0 += chunk) {
        int Bc = chunk;
        int Mi = Bc * SEQ;
        dim3 ggrid((unsigned)(Mpad / 128), 6);

        embed_kernel<<<Bc * SEQ, 256, 0, stream>>>(
            x + (size_t)b0 * LIN, conv_w, conv_b, bn_g, bn_b, bn_m, bn_v, pe, Xb);

        // --- attention block 1 ---
        gemm_qkv_mfma<<<ggrid, 256, 0, stream>>>(Xb, Wb, Qb, Kb, Vb, Mi);
        attn_kernel<<<Bc * HEADS, 256, 0, stream>>>(Qb, Kb, Vb, X);
        ln_bf16_pe_kernel<<<Mi, 256, 0, stream>>>(X, lnA1_g, lnA1_b, pe, Xb);

        // --- attention block 2 ---
        gemm_qkv_mfma<<<ggrid, 256, 0, stream>>>(Xb, Wb + 3 * wN, Qb, Kb, Vb, Mi);
        attn_kernel<<<Bc * HEADS, 256, 0, stream>>>(Qb, Kb, Vb, X);
        ln2x_kernel<<<Mi, 256, 0, stream>>>(X, lnA2_g, lnA2_b, ln2_g, ln2_b);

        final_kernel<<<Bc, 256, 0, stream>>>(X, out_w, out_b, out + (size_t)b0 * 10);
    }
}

// Round 3
// 642.824 us; speedup vs baseline: 3.6368x; 2.2447x over previous
//
#include <hip/hip_runtime.h>
#include <hip/hip_bf16.h>
#include <math.h>

#define B_TOT 512
#define SEQ   179
#define EMB   256
#define HEADS 8
#define HD    32
#define LIN   720
#define EPSV  1e-5f

typedef __attribute__((ext_vector_type(8))) short bf16x8;
typedef __attribute__((ext_vector_type(4))) float f32x4;

__device__ __forceinline__ float bf_lo(unsigned u) { return __uint_as_float(u << 16); }
__device__ __forceinline__ float bf_hi(unsigned u) { return __uint_as_float(u & 0xffff0000u); }
__device__ __forceinline__ short f2bf(float f) {          // RNE f32->bf16 bits
    unsigned u = __float_as_uint(f);
    return (short)((u + 0x7fff + ((u >> 16) & 1)) >> 16);
}

// ---------------------------------------------------------------- PE table
__global__ void pe_kernel(float* __restrict__ pe) {
    int idx = blockIdx.x * 256 + threadIdx.x;
    if (idx >= SEQ * EMB) return;
    int s = idx / EMB, e = idx % EMB;
    int i = e >> 1;
    float dv  = expf((float)(2 * i) * (-9.210340371976184f / (float)EMB));
    float ang = (float)s * dv * ((float)EMB / (float)SEQ);
    pe[idx] = (e & 1) ? cosf(ang) : sinf(ang);
}

// ----------------------------------------------------- f32 -> bf16 convert
__global__ void cvt_bf16_kernel(const float* __restrict__ src,
                                __hip_bfloat16* __restrict__ dst, int n) {
    int i = (blockIdx.x * 256 + threadIdx.x) * 4;
    if (i < n) {
        float4 v = *reinterpret_cast<const float4*>(&src[i]);
        dst[i + 0] = __float2bfloat16(v.x);
        dst[i + 1] = __float2bfloat16(v.y);
        dst[i + 2] = __float2bfloat16(v.z);
        dst[i + 3] = __float2bfloat16(v.w);
    }
}

// ------------------------ conv(stride4,K8) + BN + ReLU + PE -> bf16 X
__global__ __launch_bounds__(256) void embed_kernel(
    const float* __restrict__ x, const float* __restrict__ cw,
    const float* __restrict__ cb, const float* __restrict__ g,
    const float* __restrict__ bb, const float* __restrict__ mean,
    const float* __restrict__ var, const float* __restrict__ pe,
    __hip_bfloat16* __restrict__ Xb)
{
    int bs = blockIdx.x;
    int b  = bs / SEQ, s = bs % SEQ;
    int e  = threadIdx.x;
    __shared__ float xin[8];
    if (threadIdx.x < 8) xin[threadIdx.x] = x[(size_t)b * LIN + s * 4 + threadIdx.x];
    __syncthreads();
    float acc = cb[e];
#pragma unroll
    for (int j = 0; j < 8; ++j) acc += xin[j] * cw[e * 8 + j];
    acc = (acc - mean[e]) * (g[e] * rsqrtf(var[e] + EPSV)) + bb[e];
    acc = fmaxf(acc, 0.f);
    Xb[(size_t)bs * EMB + e] = __float2bfloat16(acc + pe[s * EMB + e]);
}

// ---------------- MFMA bf16 GEMM: C[m,n] = sum_k A[m,k] * W[n,k], C in bf16
__global__ __launch_bounds__(256) void gemm_qkv_mfma(
    const __hip_bfloat16* __restrict__ A,    // [Mpad][256]
    const __hip_bfloat16* __restrict__ Wset, // [3][256][256]
    __hip_bfloat16* __restrict__ Q, __hip_bfloat16* __restrict__ K,
    __hip_bfloat16* __restrict__ V, int M)
{
    int by = blockIdx.y;                       // 0..5
    int wsel = by >> 1;
    const __hip_bfloat16* W = Wset + (size_t)wsel * EMB * EMB;
    __hip_bfloat16* C = (wsel == 0) ? Q : (wsel == 1 ? K : V);
    int nbase = (by & 1) * 128;
    int mbase = blockIdx.x * 128;

    __shared__ __hip_bfloat16 As[128][64];
    __shared__ __hip_bfloat16 Bs[128][64];

    int tid  = threadIdx.x;
    int wave = tid >> 6, lane = tid & 63;
    int wr = wave >> 1, wc = wave & 1;

    int r0   = tid >> 3;
    int srcs = (tid & 7) ^ (r0 & 7);
    const __hip_bfloat16* gA = A + (size_t)(mbase + r0) * EMB + srcs * 8;
    const __hip_bfloat16* gB = W + (size_t)(nbase + r0) * EMB + srcs * 8;

    f32x4 acc[4][4];
#pragma unroll
    for (int i = 0; i < 4; ++i)
#pragma unroll
        for (int j = 0; j < 4; ++j) acc[i][j] = (f32x4){0.f, 0.f, 0.f, 0.f};

    for (int kt = 0; kt < EMB; kt += 64) {
        if (kt) __syncthreads();
#pragma unroll
        for (int i = 0; i < 4; ++i) {
            __hip_bfloat16* l = &As[0][0] + i * 2048 + tid * 8;
            __builtin_amdgcn_global_load_lds(
                (const __attribute__((address_space(1))) void*)(gA + (size_t)i * 32 * EMB + kt),
                (__attribute__((address_space(3))) void*)l, 16, 0, 0);
        }
#pragma unroll
        for (int i = 0; i < 4; ++i) {
            __hip_bfloat16* l = &Bs[0][0] + i * 2048 + tid * 8;
            __builtin_amdgcn_global_load_lds(
                (const __attribute__((address_space(1))) void*)(gB + (size_t)i * 32 * EMB + kt),
                (__attribute__((address_space(3))) void*)l, 16, 0, 0);
        }
        asm volatile("s_waitcnt vmcnt(0)" ::: "memory");
        __syncthreads();

#pragma unroll
        for (int kk = 0; kk < 2; ++kk) {
            bf16x8 af[4], bfr[4];
            int sg = kk * 4 + (lane >> 4);
#pragma unroll
            for (int mi = 0; mi < 4; ++mi) {
                int row = wr * 64 + mi * 16 + (lane & 15);
                int sl  = sg ^ (row & 7);
                af[mi] = *reinterpret_cast<const bf16x8*>(&As[row][sl * 8]);
            }
#pragma unroll
            for (int ni = 0; ni < 4; ++ni) {
                int row = wc * 64 + ni * 16 + (lane & 15);
                int sl  = sg ^ (row & 7);
                bfr[ni] = *reinterpret_cast<const bf16x8*>(&Bs[row][sl * 8]);
            }
#pragma unroll
            for (int mi = 0; mi < 4; ++mi)
#pragma unroll
                for (int ni = 0; ni < 4; ++ni)
                    acc[mi][ni] = __builtin_amdgcn_mfma_f32_16x16x32_bf16(
                        af[mi], bfr[ni], acc[mi][ni], 0, 0, 0);
        }
    }

    int rg = lane >> 4, cli = lane & 15;
#pragma unroll
    for (int mi = 0; mi < 4; ++mi)
#pragma unroll
        for (int j = 0; j < 4; ++j) {
            int m = mbase + wr * 64 + mi * 16 + rg * 4 + j;
            if (m < M) {
#pragma unroll
                for (int ni = 0; ni < 4; ++ni)
                    C[(size_t)m * EMB + nbase + wc * 64 + ni * 16 + cli] =
                        __float2bfloat16(acc[mi][ni][j]);
            }
        }
}

// ---------------- MFMA flash attention: block per (b,h), 4 waves x 48 rows
__global__ __launch_bounds__(256) void attn_mfma_kernel(
    const __hip_bfloat16* __restrict__ Qb, const __hip_bfloat16* __restrict__ Kb,
    const __hip_bfloat16* __restrict__ Vb, float* __restrict__ O)
{
    int bh = blockIdx.x;
    int b = bh >> 3, h = bh & 7;
    const size_t base = (size_t)b * SEQ * EMB + (size_t)h * HD;

    __shared__ short K_lds[192][40];      // [t][d], pad 40 -> 2-way free
    __shared__ short Vt_lds[32][216];     // [d][t], pad 216 -> 2-way free
    __shared__ short P_lds[4][16][216];   // per-wave P transpose buffer

    int tid  = threadIdx.x;
    int wave = tid >> 6, lane = tid & 63;
    int cl = lane & 15, rg = lane >> 4;

    // ---- stage K row-major + V transposed (zero the t-padding)
    for (int u = tid; u < 192 * 4; u += 256) {
        int t = u >> 2, d0 = (u & 3) << 3;
        if (t < SEQ) {
            uint4 kv = *reinterpret_cast<const uint4*>(&Kb[base + (size_t)t * EMB + d0]);
            *reinterpret_cast<uint4*>(&K_lds[t][d0]) = kv;
            uint4 vv = *reinterpret_cast<const uint4*>(&Vb[base + (size_t)t * EMB + d0]);
            const unsigned short* pv = reinterpret_cast<const unsigned short*>(&vv);
#pragma unroll
            for (int i = 0; i < 8; ++i) Vt_lds[d0 + i][t] = (short)pv[i];
        } else {
            *reinterpret_cast<uint4*>(&K_lds[t][d0]) = make_uint4(0, 0, 0, 0);
#pragma unroll
            for (int i = 0; i < 8; ++i) Vt_lds[d0 + i][t] = 0;
        }
    }
    __syncthreads();

    const float csw = 0.0625f / (float)SEQ;   // scale / SEQ

    for (int qt = 0; qt < 3; ++qt) {
        int qbase = wave * 48 + qt * 16;

        // Q A-fragment: row = lane&15, k(d) = (lane>>4)*8..+7
        bf16x8 aq = {};
        int sq = qbase + cl;
        if (sq < SEQ)
            aq = *reinterpret_cast<const bf16x8*>(&Qb[base + (size_t)sq * EMB + rg * 8]);

        // ---- QK^T: 12 t-tiles, full score row in registers
        f32x4 st[12];
#pragma unroll
        for (int tt = 0; tt < 12; ++tt) {
            bf16x8 kf = *reinterpret_cast<const bf16x8*>(&K_lds[tt * 16 + cl][rg * 8]);
            st[tt] = __builtin_amdgcn_mfma_f32_16x16x32_bf16(
                aq, kf, (f32x4){0.f, 0.f, 0.f, 0.f}, 0, 0, 0);
        }

        // ---- softmax: row q = qbase + rg*4 + j, spread over 16 lanes (cl = t)
        float mrow[4] = {-1e30f, -1e30f, -1e30f, -1e30f};
#pragma unroll
        for (int tt = 0; tt < 12; ++tt)
#pragma unroll
            for (int j = 0; j < 4; ++j) {
                int s = qbase + rg * 4 + j;
                int t = tt * 16 + cl;
                float v = st[tt][j] * csw * fabsf((float)(s - t));
                if (t >= SEQ) v = -1e30f;
                st[tt][j] = v;
                mrow[j] = fmaxf(mrow[j], v);
            }
#pragma unroll
        for (int j = 0; j < 4; ++j) {
            mrow[j] = fmaxf(mrow[j], __shfl_xor(mrow[j], 1));
            mrow[j] = fmaxf(mrow[j], __shfl_xor(mrow[j], 2));
            mrow[j] = fmaxf(mrow[j], __shfl_xor(mrow[j], 4));
            mrow[j] = fmaxf(mrow[j], __shfl_xor(mrow[j], 8));
        }
        float lrow[4] = {0.f, 0.f, 0.f, 0.f};
#pragma unroll
        for (int tt = 0; tt < 12; ++tt)
#pragma unroll
            for (int j = 0; j < 4; ++j) {
                float p = __expf(st[tt][j] - mrow[j]);
                st[tt][j] = p;
                lrow[j] += p;
            }
#pragma unroll
        for (int j = 0; j < 4; ++j) {
            lrow[j] += __shfl_xor(lrow[j], 1);
            lrow[j] += __shfl_xor(lrow[j], 2);
            lrow[j] += __shfl_xor(lrow[j], 4);
            lrow[j] += __shfl_xor(lrow[j], 8);
        }

        // ---- P -> per-wave LDS (bf16), A-layout-friendly [q][t]
#pragma unroll
        for (int tt = 0; tt < 12; ++tt)
#pragma unroll
            for (int j = 0; j < 4; ++j)
                P_lds[wave][rg * 4 + j][tt * 16 + cl] = f2bf(st[tt][j]);
        asm volatile("s_waitcnt lgkmcnt(0)" ::: "memory");  // wave-local wr->rd

        // ---- PV: O[q, d0..31] = P[q,t] * V[t,d]
        f32x4 o0 = {0.f, 0.f, 0.f, 0.f}, o1 = {0.f, 0.f, 0.f, 0.f};
#pragma unroll
        for (int tc = 0; tc < 6; ++tc) {
            bf16x8 pa = *reinterpret_cast<const bf16x8*>(&P_lds[wave][cl][tc * 32 + rg * 8]);
            bf16x8 b0 = *reinterpret_cast<const bf16x8*>(&Vt_lds[cl][tc * 32 + rg * 8]);
            bf16x8 b1 = *reinterpret_cast<const bf16x8*>(&Vt_lds[16 + cl][tc * 32 + rg * 8]);
            o0 = __builtin_amdgcn_mfma_f32_16x16x32_bf16(pa, b0, o0, 0, 0, 0);
            o1 = __builtin_amdgcn_mfma_f32_16x16x32_bf16(pa, b1, o1, 0, 0, 0);
        }

        // ---- store (divide by row sum; same C-layout row mapping)
#pragma unroll
        for (int j = 0; j < 4; ++j) {
            int s = qbase + rg * 4 + j;
            if (s < SEQ) {
                float rl = 1.0f / lrow[j];
                float* op = &O[base + (size_t)s * EMB];
                op[cl]      = o0[j] * rl;
                op[16 + cl] = o1[j] * rl;
            }
        }
    }
}

// ---------------- row LayerNorm + PE, writes bf16 (feeds next GEMM)
__global__ __launch_bounds__(256) void ln_bf16_pe_kernel(
    const float* __restrict__ X, const float* __restrict__ g,
    const float* __restrict__ bb, const float* __restrict__ pe,
    __hip_bfloat16* __restrict__ Xb)
{
    int bs = blockIdx.x;
    int s  = bs % SEQ;
    int e  = threadIdx.x;
    float v = X[(size_t)bs * EMB + e];

    float sum = v, sumsq = v * v;
#pragma unroll
    for (int off = 32; off > 0; off >>= 1) {
        sum   += __shfl_down(sum, off);
        sumsq += __shfl_down(sumsq, off);
    }
    __shared__ float ps[4], pss[4];
    int wave = e >> 6, lane = e & 63;
    if (lane == 0) { ps[wave] = sum; pss[wave] = sumsq; }
    __syncthreads();
    float tot   = ps[0] + ps[1] + ps[2] + ps[3];
    float totsq = pss[0] + pss[1] + pss[2] + pss[3];
    float mu  = tot * (1.0f / EMB);
    float var = totsq * (1.0f / EMB) - mu * mu;
    float y = (v - mu) * rsqrtf(var + EPSV) * g[e] + bb[e] + pe[s * EMB + e];
    Xb[(size_t)bs * EMB + e] = __float2bfloat16(y);
}

// ---------------- fused double LayerNorm (lnA2 then ln2), f32 in-place
__global__ __launch_bounds__(256) void ln2x_kernel(
    float* __restrict__ X, const float* __restrict__ g1, const float* __restrict__ b1,
    const float* __restrict__ g2, const float* __restrict__ b2)
{
    int bs = blockIdx.x;
    int e  = threadIdx.x;
    int wave = e >> 6, lane = e & 63;
    __shared__ float ps[4], pss[4];

    float v = X[(size_t)bs * EMB + e];
    float sum = v, sumsq = v * v;
#pragma unroll
    for (int off = 32; off > 0; off >>= 1) {
        sum   += __shfl_down(sum, off);
        sumsq += __shfl_down(sumsq, off);
    }
    if (lane == 0) { ps[wave] = sum; pss[wave] = sumsq; }
    __syncthreads();
    float tot   = ps[0] + ps[1] + ps[2] + ps[3];
    float totsq = pss[0] + pss[1] + pss[2] + pss[3];
    float mu  = tot * (1.0f / EMB);
    float var = totsq * (1.0f / EMB) - mu * mu;
    float y1 = (v - mu) * rsqrtf(var + EPSV) * g1[e] + b1[e];
    __syncthreads();

    sum = y1; sumsq = y1 * y1;
#pragma unroll
    for (int off = 32; off > 0; off >>= 1) {
        sum   += __shfl_down(sum, off);
        sumsq += __shfl_down(sumsq, off);
    }
    if (lane == 0) { ps[wave] = sum; pss[wave] = sumsq; }
    __syncthreads();
    tot   = ps[0] + ps[1] + ps[2] + ps[3];
    totsq = pss[0] + pss[1] + pss[2] + pss[3];
    mu  = tot * (1.0f / EMB);
    var = totsq * (1.0f / EMB) - mu * mu;
    X[(size_t)bs * EMB + e] = (y1 - mu) * rsqrtf(var + EPSV) * g2[e] + b2[e];
}

// --------------------------------- mean-pool over SEQ + final FC [10]
__global__ __launch_bounds__(256) void final_kernel(
    const float* __restrict__ X, const float* __restrict__ ow,
    const float* __restrict__ ob, float* __restrict__ out)
{
    int b = blockIdx.x;
    int e = threadIdx.x;
    float acc = 0.f;
    for (int s = 0; s < SEQ; ++s) acc += X[((size_t)b * SEQ + s) * EMB + e];
    __shared__ float pooled[EMB];
    pooled[e] = acc * (1.0f / (float)SEQ);
    __syncthreads();
    if (e < 10) {
        float o = ob[e];
        for (int k = 0; k < EMB; ++k) o += pooled[k] * ow[e * EMB + k];
        out[b * 10 + e] = o;
    }
}

// ---------------------------------------------------------------- launch
extern "C" void kernel_launch(void* const* d_in, const int* in_sizes, int n_in,
                              void* d_out, int out_size, void* d_ws, size_t ws_size,
                              hipStream_t stream)
{
    const float* x      = (const float*)d_in[0];
    const float* conv_w = (const float*)d_in[1];
    const float* conv_b = (const float*)d_in[2];
    const float* bn_g   = (const float*)d_in[3];
    const float* bn_b   = (const float*)d_in[4];
    const float* bn_m   = (const float*)d_in[5];
    const float* bn_v   = (const float*)d_in[6];
    const float* wq1    = (const float*)d_in[7];
    const float* wk1    = (const float*)d_in[8];
    const float* wv1    = (const float*)d_in[9];
    const float* lnA1_g = (const float*)d_in[10];
    const float* lnA1_b = (const float*)d_in[11];
    const float* wq2    = (const float*)d_in[12];
    const float* wk2    = (const float*)d_in[13];
    const float* wv2    = (const float*)d_in[14];
    const float* lnA2_g = (const float*)d_in[15];
    const float* lnA2_b = (const float*)d_in[16];
    const float* ln2_g  = (const float*)d_in[17];
    const float* ln2_b  = (const float*)d_in[18];
    const float* out_w  = (const float*)d_in[19];
    const float* out_b  = (const float*)d_in[20];
    float* out = (float*)d_out;

    const size_t peN = (size_t)SEQ * EMB;
    const size_t wN  = (size_t)EMB * EMB;

    int chunk = B_TOT;
    while (chunk > 1) {
        size_t M    = (size_t)chunk * SEQ;
        size_t Mpad = (M + 127) / 128 * 128;
        size_t need = peN * 4 + 6 * wN * 2 + Mpad * EMB * 2
                    + M * EMB * 4 + 3 * M * EMB * 2;
        if (need <= ws_size) break;
        chunk >>= 1;
    }
    size_t M    = (size_t)chunk * SEQ;
    size_t Mpad = (M + 127) / 128 * 128;

    float*          pe = (float*)d_ws;
    __hip_bfloat16* Wb = (__hip_bfloat16*)(pe + peN);
    __hip_bfloat16* Xb = Wb + 6 * wN;
    float*          X  = (float*)(Xb + Mpad * EMB);
    __hip_bfloat16* Qb = (__hip_bfloat16*)(X + M * EMB);
    __hip_bfloat16* Kb = Qb + M * EMB;
    __hip_bfloat16* Vb = Kb + M * EMB;

    pe_kernel<<<(SEQ * EMB + 255) / 256, 256, 0, stream>>>(pe);

    const float* Wsrc[6] = {wq1, wk1, wv1, wq2, wk2, wv2};
    for (int w = 0; w < 6; ++w)
        cvt_bf16_kernel<<<(int)(wN / 1024), 256, 0, stream>>>(Wsrc[w], Wb + (size_t)w * wN, (int)wN);

    for (int b0 = 0; b0 < B_TOT; b0 += chunk) {
        int Bc = chunk;
        int Mi = Bc * SEQ;
        dim3 ggrid((unsigned)(Mpad / 128), 6);

        embed_kernel<<<Bc * SEQ, 256, 0, stream>>>(
            x + (size_t)b0 * LIN, conv_w, conv_b, bn_g, bn_b, bn_m, bn_v, pe, Xb);

        // --- attention block 1 ---
        gemm_qkv_mfma<<<ggrid, 256, 0, stream>>>(Xb, Wb, Qb, Kb, Vb, Mi);
        attn_mfma_kernel<<<Bc * HEADS, 256, 0, stream>>>(Qb, Kb, Vb, X);
        ln_bf16_pe_kernel<<<Mi, 256, 0, stream>>>(X, lnA1_g, lnA1_b, pe, Xb);

        // --- attention block 2 ---
        gemm_qkv_mfma<<<ggrid, 256, 0, stream>>>(Xb, Wb + 3 * wN, Qb, Kb, Vb, Mi);
        attn_mfma_kernel<<<Bc * HEADS, 256, 0, stream>>>(Qb, Kb, Vb, X);
        ln2x_kernel<<<Mi, 256, 0, stream>>>(X, lnA2_g, lnA2_b, ln2_g, ln2_b);

        final_kernel<<<Bc, 256, 0, stream>>>(X, out_w, out_b, out + (size_t)b0 * 10);
    }
}

// Round 4
// 493.804 us; speedup vs baseline: 4.7342x; 1.3018x over previous
//
#include <hip/hip_runtime.h>
#include <hip/hip_bf16.h>
#include <math.h>

#define B_TOT 512
#define SEQ   179
#define EMB   256
#define HEADS 8
#define HD    32
#define LIN   720
#define EPSV  1e-5f

typedef __attribute__((ext_vector_type(8))) short bf16x8;
typedef __attribute__((ext_vector_type(4))) float f32x4;

__device__ __forceinline__ float bf2f(unsigned short u) {
    return __uint_as_float(((unsigned)u) << 16);
}
__device__ __forceinline__ short f2bf(float f) {          // RNE f32->bf16 bits
    unsigned u = __float_as_uint(f);
    return (short)((u + 0x7fff + ((u >> 16) & 1)) >> 16);
}

// ---------------------------------------------------------------- PE table
__global__ void pe_kernel(float* __restrict__ pe) {
    int idx = blockIdx.x * 256 + threadIdx.x;
    if (idx >= SEQ * EMB) return;
    int s = idx / EMB, e = idx % EMB;
    int i = e >> 1;
    float dv  = expf((float)(2 * i) * (-9.210340371976184f / (float)EMB));
    float ang = (float)s * dv * ((float)EMB / (float)SEQ);
    pe[idx] = (e & 1) ? cosf(ang) : sinf(ang);
}

// ------------------------------------- f32 -> bf16 convert, 6 weights at once
__global__ void cvt6_kernel(const float* __restrict__ s0, const float* __restrict__ s1,
                            const float* __restrict__ s2, const float* __restrict__ s3,
                            const float* __restrict__ s4, const float* __restrict__ s5,
                            __hip_bfloat16* __restrict__ dst, int n) {
    int w = blockIdx.y;
    const float* src = (w == 0) ? s0 : (w == 1) ? s1 : (w == 2) ? s2
                     : (w == 3) ? s3 : (w == 4) ? s4 : s5;
    __hip_bfloat16* d = dst + (size_t)w * n;
    int i = (blockIdx.x * 256 + threadIdx.x) * 4;
    if (i < n) {
        float4 v = *reinterpret_cast<const float4*>(&src[i]);
        d[i + 0] = __float2bfloat16(v.x);
        d[i + 1] = __float2bfloat16(v.y);
        d[i + 2] = __float2bfloat16(v.z);
        d[i + 3] = __float2bfloat16(v.w);
    }
}

// ------------------------ conv(stride4,K8) + BN + ReLU + PE -> bf16 X
__global__ __launch_bounds__(256) void embed_kernel(
    const float* __restrict__ x, const float* __restrict__ cw,
    const float* __restrict__ cb, const float* __restrict__ g,
    const float* __restrict__ bb, const float* __restrict__ mean,
    const float* __restrict__ var, const float* __restrict__ pe,
    __hip_bfloat16* __restrict__ Xb)
{
    int bs = blockIdx.x;
    int b  = bs / SEQ, s = bs % SEQ;
    int e  = threadIdx.x;
    __shared__ float xin[8];
    if (threadIdx.x < 8) xin[threadIdx.x] = x[(size_t)b * LIN + s * 4 + threadIdx.x];
    __syncthreads();
    float acc = cb[e];
#pragma unroll
    for (int j = 0; j < 8; ++j) acc += xin[j] * cw[e * 8 + j];
    acc = (acc - mean[e]) * (g[e] * rsqrtf(var[e] + EPSV)) + bb[e];
    acc = fmaxf(acc, 0.f);
    Xb[(size_t)bs * EMB + e] = __float2bfloat16(acc + pe[s * EMB + e]);
}

// ---------------- MFMA bf16 GEMM: C[m,n] = sum_k A[m,k] * W[n,k], C in bf16
__global__ __launch_bounds__(256) void gemm_qkv_mfma(
    const __hip_bfloat16* __restrict__ A,    // [Mpad][256]
    const __hip_bfloat16* __restrict__ Wset, // [3][256][256]
    __hip_bfloat16* __restrict__ Q, __hip_bfloat16* __restrict__ K,
    __hip_bfloat16* __restrict__ V, int M)
{
    int by = blockIdx.y;                       // 0..5
    int wsel = by >> 1;
    const __hip_bfloat16* W = Wset + (size_t)wsel * EMB * EMB;
    __hip_bfloat16* C = (wsel == 0) ? Q : (wsel == 1 ? K : V);
    int nbase = (by & 1) * 128;
    int mbase = blockIdx.x * 128;

    __shared__ __hip_bfloat16 As[128][64];
    __shared__ __hip_bfloat16 Bs[128][64];

    int tid  = threadIdx.x;
    int wave = tid >> 6, lane = tid & 63;
    int wr = wave >> 1, wc = wave & 1;

    int r0   = tid >> 3;
    int srcs = (tid & 7) ^ (r0 & 7);
    const __hip_bfloat16* gA = A + (size_t)(mbase + r0) * EMB + srcs * 8;
    const __hip_bfloat16* gB = W + (size_t)(nbase + r0) * EMB + srcs * 8;

    f32x4 acc[4][4];
#pragma unroll
    for (int i = 0; i < 4; ++i)
#pragma unroll
        for (int j = 0; j < 4; ++j) acc[i][j] = (f32x4){0.f, 0.f, 0.f, 0.f};

    for (int kt = 0; kt < EMB; kt += 64) {
        if (kt) __syncthreads();
#pragma unroll
        for (int i = 0; i < 4; ++i) {
            __hip_bfloat16* l = &As[0][0] + i * 2048 + tid * 8;
            __builtin_amdgcn_global_load_lds(
                (const __attribute__((address_space(1))) void*)(gA + (size_t)i * 32 * EMB + kt),
                (__attribute__((address_space(3))) void*)l, 16, 0, 0);
        }
#pragma unroll
        for (int i = 0; i < 4; ++i) {
            __hip_bfloat16* l = &Bs[0][0] + i * 2048 + tid * 8;
            __builtin_amdgcn_global_load_lds(
                (const __attribute__((address_space(1))) void*)(gB + (size_t)i * 32 * EMB + kt),
                (__attribute__((address_space(3))) void*)l, 16, 0, 0);
        }
        asm volatile("s_waitcnt vmcnt(0)" ::: "memory");
        __syncthreads();

#pragma unroll
        for (int kk = 0; kk < 2; ++kk) {
            bf16x8 af[4], bfr[4];
            int sg = kk * 4 + (lane >> 4);
#pragma unroll
            for (int mi = 0; mi < 4; ++mi) {
                int row = wr * 64 + mi * 16 + (lane & 15);
                int sl  = sg ^ (row & 7);
                af[mi] = *reinterpret_cast<const bf16x8*>(&As[row][sl * 8]);
            }
#pragma unroll
            for (int ni = 0; ni < 4; ++ni) {
                int row = wc * 64 + ni * 16 + (lane & 15);
                int sl  = sg ^ (row & 7);
                bfr[ni] = *reinterpret_cast<const bf16x8*>(&Bs[row][sl * 8]);
            }
#pragma unroll
            for (int mi = 0; mi < 4; ++mi)
#pragma unroll
                for (int ni = 0; ni < 4; ++ni)
                    acc[mi][ni] = __builtin_amdgcn_mfma_f32_16x16x32_bf16(
                        af[mi], bfr[ni], acc[mi][ni], 0, 0, 0);
        }
    }

    int rg = lane >> 4, cli = lane & 15;
#pragma unroll
    for (int mi = 0; mi < 4; ++mi)
#pragma unroll
        for (int j = 0; j < 4; ++j) {
            int m = mbase + wr * 64 + mi * 16 + rg * 4 + j;
            if (m < M) {
#pragma unroll
                for (int ni = 0; ni < 4; ++ni)
                    C[(size_t)m * EMB + nbase + wc * 64 + ni * 16 + cli] =
                        __float2bfloat16(acc[mi][ni][j]);
            }
        }
}

// ---------------- MFMA flash attention: block per (b,h), 4 waves x 48 rows
// Output written as bf16.
__global__ __launch_bounds__(256) void attn_mfma_kernel(
    const __hip_bfloat16* __restrict__ Qb, const __hip_bfloat16* __restrict__ Kb,
    const __hip_bfloat16* __restrict__ Vb, __hip_bfloat16* __restrict__ O)
{
    int bh = blockIdx.x;
    int b = bh >> 3, h = bh & 7;
    const size_t base = (size_t)b * SEQ * EMB + (size_t)h * HD;

    __shared__ short K_lds[192][40];      // [t][d], pad 40 -> 2-way free
    __shared__ short Vt_lds[32][216];     // [d][t], pad 216 -> 2-way free
    __shared__ short P_lds[4][16][216];   // per-wave P transpose buffer

    int tid  = threadIdx.x;
    int wave = tid >> 6, lane = tid & 63;
    int cl = lane & 15, rg = lane >> 4;

    // ---- stage K row-major + V transposed (zero the t-padding)
    for (int u = tid; u < 192 * 4; u += 256) {
        int t = u >> 2, d0 = (u & 3) << 3;
        if (t < SEQ) {
            uint4 kv = *reinterpret_cast<const uint4*>(&Kb[base + (size_t)t * EMB + d0]);
            *reinterpret_cast<uint4*>(&K_lds[t][d0]) = kv;
            uint4 vv = *reinterpret_cast<const uint4*>(&Vb[base + (size_t)t * EMB + d0]);
            const unsigned short* pv = reinterpret_cast<const unsigned short*>(&vv);
#pragma unroll
            for (int i = 0; i < 8; ++i) Vt_lds[d0 + i][t] = (short)pv[i];
        } else {
            *reinterpret_cast<uint4*>(&K_lds[t][d0]) = make_uint4(0, 0, 0, 0);
#pragma unroll
            for (int i = 0; i < 8; ++i) Vt_lds[d0 + i][t] = 0;
        }
    }
    __syncthreads();

    const float csw = 0.0625f / (float)SEQ;   // scale / SEQ

    for (int qt = 0; qt < 3; ++qt) {
        int qbase = wave * 48 + qt * 16;

        bf16x8 aq = {};
        int sq = qbase + cl;
        if (sq < SEQ)
            aq = *reinterpret_cast<const bf16x8*>(&Qb[base + (size_t)sq * EMB + rg * 8]);

        // ---- QK^T: 12 t-tiles, full score row in registers
        f32x4 st[12];
#pragma unroll
        for (int tt = 0; tt < 12; ++tt) {
            bf16x8 kf = *reinterpret_cast<const bf16x8*>(&K_lds[tt * 16 + cl][rg * 8]);
            st[tt] = __builtin_amdgcn_mfma_f32_16x16x32_bf16(
                aq, kf, (f32x4){0.f, 0.f, 0.f, 0.f}, 0, 0, 0);
        }

        // ---- softmax: row q = qbase + rg*4 + j, spread over 16 lanes (cl = t)
        float mrow[4] = {-1e30f, -1e30f, -1e30f, -1e30f};
#pragma unroll
        for (int tt = 0; tt < 12; ++tt)
#pragma unroll
            for (int j = 0; j < 4; ++j) {
                int s = qbase + rg * 4 + j;
                int t = tt * 16 + cl;
                float v = st[tt][j] * csw * fabsf((float)(s - t));
                if (t >= SEQ) v = -1e30f;
                st[tt][j] = v;
                mrow[j] = fmaxf(mrow[j], v);
            }
#pragma unroll
        for (int j = 0; j < 4; ++j) {
            mrow[j] = fmaxf(mrow[j], __shfl_xor(mrow[j], 1));
            mrow[j] = fmaxf(mrow[j], __shfl_xor(mrow[j], 2));
            mrow[j] = fmaxf(mrow[j], __shfl_xor(mrow[j], 4));
            mrow[j] = fmaxf(mrow[j], __shfl_xor(mrow[j], 8));
        }
        float lrow[4] = {0.f, 0.f, 0.f, 0.f};
#pragma unroll
        for (int tt = 0; tt < 12; ++tt)
#pragma unroll
            for (int j = 0; j < 4; ++j) {
                float p = __expf(st[tt][j] - mrow[j]);
                st[tt][j] = p;
                lrow[j] += p;
            }
#pragma unroll
        for (int j = 0; j < 4; ++j) {
            lrow[j] += __shfl_xor(lrow[j], 1);
            lrow[j] += __shfl_xor(lrow[j], 2);
            lrow[j] += __shfl_xor(lrow[j], 4);
            lrow[j] += __shfl_xor(lrow[j], 8);
        }

        // ---- P -> per-wave LDS (bf16), [q][t]
#pragma unroll
        for (int tt = 0; tt < 12; ++tt)
#pragma unroll
            for (int j = 0; j < 4; ++j)
                P_lds[wave][rg * 4 + j][tt * 16 + cl] = f2bf(st[tt][j]);
        asm volatile("s_waitcnt lgkmcnt(0)" ::: "memory");  // wave-local wr->rd

        // ---- PV: O[q, d0..31] = P[q,t] * V[t,d]
        f32x4 o0 = {0.f, 0.f, 0.f, 0.f}, o1 = {0.f, 0.f, 0.f, 0.f};
#pragma unroll
        for (int tc = 0; tc < 6; ++tc) {
            bf16x8 pa = *reinterpret_cast<const bf16x8*>(&P_lds[wave][cl][tc * 32 + rg * 8]);
            bf16x8 b0 = *reinterpret_cast<const bf16x8*>(&Vt_lds[cl][tc * 32 + rg * 8]);
            bf16x8 b1 = *reinterpret_cast<const bf16x8*>(&Vt_lds[16 + cl][tc * 32 + rg * 8]);
            o0 = __builtin_amdgcn_mfma_f32_16x16x32_bf16(pa, b0, o0, 0, 0, 0);
            o1 = __builtin_amdgcn_mfma_f32_16x16x32_bf16(pa, b1, o1, 0, 0, 0);
        }

        // ---- store bf16 (divide by row sum)
#pragma unroll
        for (int j = 0; j < 4; ++j) {
            int s = qbase + rg * 4 + j;
            if (s < SEQ) {
                float rl = 1.0f / lrow[j];
                __hip_bfloat16* op = &O[base + (size_t)s * EMB];
                op[cl]      = __float2bfloat16(o0[j] * rl);
                op[16 + cl] = __float2bfloat16(o1[j] * rl);
            }
        }
    }
}

// ---------------- row LayerNorm + PE: bf16 in (attn out), bf16 out (GEMM in)
__global__ __launch_bounds__(256) void ln_bf16_pe_kernel(
    const __hip_bfloat16* __restrict__ X, const float* __restrict__ g,
    const float* __restrict__ bb, const float* __restrict__ pe,
    __hip_bfloat16* __restrict__ Xb)
{
    int bs = blockIdx.x;
    int s  = bs % SEQ;
    int e  = threadIdx.x;
    float v = __bfloat162float(X[(size_t)bs * EMB + e]);

    float sum = v, sumsq = v * v;
#pragma unroll
    for (int off = 32; off > 0; off >>= 1) {
        sum   += __shfl_down(sum, off);
        sumsq += __shfl_down(sumsq, off);
    }
    __shared__ float ps[4], pss[4];
    int wave = e >> 6, lane = e & 63;
    if (lane == 0) { ps[wave] = sum; pss[wave] = sumsq; }
    __syncthreads();
    float tot   = ps[0] + ps[1] + ps[2] + ps[3];
    float totsq = pss[0] + pss[1] + pss[2] + pss[3];
    float mu  = tot * (1.0f / EMB);
    float var = totsq * (1.0f / EMB) - mu * mu;
    float y = (v - mu) * rsqrtf(var + EPSV) * g[e] + bb[e] + pe[s * EMB + e];
    Xb[(size_t)bs * EMB + e] = __float2bfloat16(y);
}

// ------- fused: LN(lnA2) -> LN(ln2) -> mean-pool over SEQ -> FC[10]
// block per batch element; wave-per-row (shfl-only row reductions)
__global__ __launch_bounds__(256) void lnfc_kernel(
    const __hip_bfloat16* __restrict__ X,
    const float* __restrict__ g1, const float* __restrict__ b1,
    const float* __restrict__ g2, const float* __restrict__ b2,
    const float* __restrict__ ow, const float* __restrict__ ob,
    float* __restrict__ out)
{
    int b    = blockIdx.x;
    int tid  = threadIdx.x;
    int wave = tid >> 6, lane = tid & 63;

    // per-lane column set: c_j = lane + 64*j
    float g1v[4], b1v[4], g2v[4], b2v[4], pooled[4];
#pragma unroll
    for (int j = 0; j < 4; ++j) {
        int c = lane + 64 * j;
        g1v[j] = g1[c]; b1v[j] = b1[c];
        g2v[j] = g2[c]; b2v[j] = b2[c];
        pooled[j] = 0.f;
    }

    for (int s = wave; s < SEQ; s += 4) {
        const __hip_bfloat16* row = &X[((size_t)b * SEQ + s) * EMB];
        float v[4];
#pragma unroll
        for (int j = 0; j < 4; ++j) v[j] = __bfloat162float(row[lane + 64 * j]);

        float sum = v[0] + v[1] + v[2] + v[3];
        float sq  = v[0]*v[0] + v[1]*v[1] + v[2]*v[2] + v[3]*v[3];
#pragma unroll
        for (int off = 32; off > 0; off >>= 1) {
            sum += __shfl_xor(sum, off);
            sq  += __shfl_xor(sq,  off);
        }
        float mu  = sum * (1.0f / EMB);
        float var = sq * (1.0f / EMB) - mu * mu;
        float is  = rsqrtf(var + EPSV);
        float y[4];
#pragma unroll
        for (int j = 0; j < 4; ++j) y[j] = (v[j] - mu) * is * g1v[j] + b1v[j];

        sum = y[0] + y[1] + y[2] + y[3];
        sq  = y[0]*y[0] + y[1]*y[1] + y[2]*y[2] + y[3]*y[3];
#pragma unroll
        for (int off = 32; off > 0; off >>= 1) {
            sum += __shfl_xor(sum, off);
            sq  += __shfl_xor(sq,  off);
        }
        mu  = sum * (1.0f / EMB);
        var = sq * (1.0f / EMB) - mu * mu;
        is  = rsqrtf(var + EPSV);
#pragma unroll
        for (int j = 0; j < 4; ++j) pooled[j] += (y[j] - mu) * is * g2v[j] + b2v[j];
    }

    __shared__ float pp[4][EMB];
#pragma unroll
    for (int j = 0; j < 4; ++j) pp[wave][lane + 64 * j] = pooled[j];
    __syncthreads();
    __shared__ float pool[EMB];
    pool[tid] = (pp[0][tid] + pp[1][tid] + pp[2][tid] + pp[3][tid]) * (1.0f / (float)SEQ);
    __syncthreads();
    if (tid < 10) {
        float o = ob[tid];
        for (int k = 0; k < EMB; ++k) o += pool[k] * ow[tid * EMB + k];
        out[b * 10 + tid] = o;
    }
}

// ---------------------------------------------------------------- launch
extern "C" void kernel_launch(void* const* d_in, const int* in_sizes, int n_in,
                              void* d_out, int out_size, void* d_ws, size_t ws_size,
                              hipStream_t stream)
{
    const float* x      = (const float*)d_in[0];
    const float* conv_w = (const float*)d_in[1];
    const float* conv_b = (const float*)d_in[2];
    const float* bn_g   = (const float*)d_in[3];
    const float* bn_b   = (const float*)d_in[4];
    const float* bn_m   = (const float*)d_in[5];
    const float* bn_v   = (const float*)d_in[6];
    const float* wq1    = (const float*)d_in[7];
    const float* wk1    = (const float*)d_in[8];
    const float* wv1    = (const float*)d_in[9];
    const float* lnA1_g = (const float*)d_in[10];
    const float* lnA1_b = (const float*)d_in[11];
    const float* wq2    = (const float*)d_in[12];
    const float* wk2    = (const float*)d_in[13];
    const float* wv2    = (const float*)d_in[14];
    const float* lnA2_g = (const float*)d_in[15];
    const float* lnA2_b = (const float*)d_in[16];
    const float* ln2_g  = (const float*)d_in[17];
    const float* ln2_b  = (const float*)d_in[18];
    const float* out_w  = (const float*)d_in[19];
    const float* out_b  = (const float*)d_in[20];
    float* out = (float*)d_out;

    const size_t peN = (size_t)SEQ * EMB;
    const size_t wN  = (size_t)EMB * EMB;

    // pe(f32) + Wb(6 bf16) + Xb(bf16, Mpad) + Ob/Qb/Kb/Vb(bf16, M)
    int chunk = B_TOT;
    while (chunk > 1) {
        size_t M    = (size_t)chunk * SEQ;
        size_t Mpad = (M + 127) / 128 * 128;
        size_t need = peN * 4 + 6 * wN * 2 + (Mpad + 4 * M) * EMB * 2;
        if (need <= ws_size) break;
        chunk >>= 1;
    }
    size_t M    = (size_t)chunk * SEQ;
    size_t Mpad = (M + 127) / 128 * 128;

    float*          pe = (float*)d_ws;
    __hip_bfloat16* Wb = (__hip_bfloat16*)(pe + peN);
    __hip_bfloat16* Xb = Wb + 6 * wN;
    __hip_bfloat16* Ob = Xb + Mpad * EMB;
    __hip_bfloat16* Qb = Ob + M * EMB;
    __hip_bfloat16* Kb = Qb + M * EMB;
    __hip_bfloat16* Vb = Kb + M * EMB;

    pe_kernel<<<(SEQ * EMB + 255) / 256, 256, 0, stream>>>(pe);
    {
        dim3 cg((unsigned)(wN / 1024), 6);
        cvt6_kernel<<<cg, 256, 0, stream>>>(wq1, wk1, wv1, wq2, wk2, wv2, Wb, (int)wN);
    }

    for (int b0 = 0; b0 < B_TOT; b0 += chunk) {
        int Bc = chunk;
        int Mi = Bc * SEQ;
        dim3 ggrid((unsigned)(Mpad / 128), 6);

        embed_kernel<<<Bc * SEQ, 256, 0, stream>>>(
            x + (size_t)b0 * LIN, conv_w, conv_b, bn_g, bn_b, bn_m, bn_v, pe, Xb);

        // --- attention block 1 ---
        gemm_qkv_mfma<<<ggrid, 256, 0, stream>>>(Xb, Wb, Qb, Kb, Vb, Mi);
        attn_mfma_kernel<<<Bc * HEADS, 256, 0, stream>>>(Qb, Kb, Vb, Ob);
        ln_bf16_pe_kernel<<<Mi, 256, 0, stream>>>(Ob, lnA1_g, lnA1_b, pe, Xb);

        // --- attention block 2 ---
        gemm_qkv_mfma<<<ggrid, 256, 0, stream>>>(Xb, Wb + 3 * wN, Qb, Kb, Vb, Mi);
        attn_mfma_kernel<<<Bc * HEADS, 256, 0, stream>>>(Qb, Kb, Vb, Ob);
        lnfc_kernel<<<Bc, 256, 0, stream>>>(Ob, lnA2_g, lnA2_b, ln2_g, ln2_b,
                                            out_w, out_b, out + (size_t)b0 * 10);
    }
}

// Round 6
// 462.822 us; speedup vs baseline: 5.0512x; 1.0669x over previous
//
#include <hip/hip_runtime.h>
#include <hip/hip_bf16.h>
#include <math.h>

#define B_TOT 512
#define SEQ   179
#define EMB   256
#define HEADS 8
#define HD    32
#define LIN   720
#define EPSV  1e-5f

typedef __attribute__((ext_vector_type(8))) short bf16x8;
typedef __attribute__((ext_vector_type(4))) float f32x4;

__device__ __forceinline__ short f2bf(float f) {          // RNE f32->bf16 bits
    unsigned u = __float_as_uint(f);
    return (short)((u + 0x7fff + ((u >> 16) & 1)) >> 16);
}

// ---------------------------------------------------------------- PE table
__global__ void pe_kernel(float* __restrict__ pe) {
    int idx = blockIdx.x * 256 + threadIdx.x;
    if (idx >= SEQ * EMB) return;
    int s = idx / EMB, e = idx % EMB;
    int i = e >> 1;
    float dv  = expf((float)(2 * i) * (-9.210340371976184f / (float)EMB));
    float ang = (float)s * dv * ((float)EMB / (float)SEQ);
    pe[idx] = (e & 1) ? cosf(ang) : sinf(ang);
}

// ------------------------------------- f32 -> bf16 convert, 6 weights at once
__global__ void cvt6_kernel(const float* __restrict__ s0, const float* __restrict__ s1,
                            const float* __restrict__ s2, const float* __restrict__ s3,
                            const float* __restrict__ s4, const float* __restrict__ s5,
                            __hip_bfloat16* __restrict__ dst, int n) {
    int w = blockIdx.y;
    const float* src = (w == 0) ? s0 : (w == 1) ? s1 : (w == 2) ? s2
                     : (w == 3) ? s3 : (w == 4) ? s4 : s5;
    __hip_bfloat16* d = dst + (size_t)w * n;
    int i = (blockIdx.x * 256 + threadIdx.x) * 4;
    if (i < n) {
        float4 v = *reinterpret_cast<const float4*>(&src[i]);
        d[i + 0] = __float2bfloat16(v.x);
        d[i + 1] = __float2bfloat16(v.y);
        d[i + 2] = __float2bfloat16(v.z);
        d[i + 3] = __float2bfloat16(v.w);
    }
}

// ------------------------ conv(stride4,K8) + BN + ReLU + PE -> bf16 X
__global__ __launch_bounds__(256) void embed_kernel(
    const float* __restrict__ x, const float* __restrict__ cw,
    const float* __restrict__ cb, const float* __restrict__ g,
    const float* __restrict__ bb, const float* __restrict__ mean,
    const float* __restrict__ var, const float* __restrict__ pe,
    __hip_bfloat16* __restrict__ Xb)
{
    int bs = blockIdx.x;
    int b  = bs / SEQ, s = bs % SEQ;
    int e  = threadIdx.x;
    __shared__ float xin[8];
    if (threadIdx.x < 8) xin[threadIdx.x] = x[(size_t)b * LIN + s * 4 + threadIdx.x];
    __syncthreads();
    float acc = cb[e];
#pragma unroll
    for (int j = 0; j < 8; ++j) acc += xin[j] * cw[e * 8 + j];
    acc = (acc - mean[e]) * (g[e] * rsqrtf(var[e] + EPSV)) + bb[e];
    acc = fmaxf(acc, 0.f);
    Xb[(size_t)bs * EMB + e] = __float2bfloat16(acc + pe[s * EMB + e]);
}

// ---------------- MFMA bf16 GEMM: C[m,n] = sum_k A[m,k] * W[n,k], C in bf16
__global__ __launch_bounds__(256) void gemm_qkv_mfma(
    const __hip_bfloat16* __restrict__ A,    // [Mpad][256]
    const __hip_bfloat16* __restrict__ Wset, // [3][256][256]
    __hip_bfloat16* __restrict__ Q, __hip_bfloat16* __restrict__ K,
    __hip_bfloat16* __restrict__ V, int M)
{
    int by = blockIdx.y;                       // 0..5
    int wsel = by >> 1;
    const __hip_bfloat16* W = Wset + (size_t)wsel * EMB * EMB;
    __hip_bfloat16* C = (wsel == 0) ? Q : (wsel == 1 ? K : V);
    int nbase = (by & 1) * 128;
    int mbase = blockIdx.x * 128;

    __shared__ __hip_bfloat16 As[128][64];
    __shared__ __hip_bfloat16 Bs[128][64];

    int tid  = threadIdx.x;
    int wave = tid >> 6, lane = tid & 63;
    int wr = wave >> 1, wc = wave & 1;

    int r0   = tid >> 3;
    int srcs = (tid & 7) ^ (r0 & 7);
    const __hip_bfloat16* gA = A + (size_t)(mbase + r0) * EMB + srcs * 8;
    const __hip_bfloat16* gB = W + (size_t)(nbase + r0) * EMB + srcs * 8;

    f32x4 acc[4][4];
#pragma unroll
    for (int i = 0; i < 4; ++i)
#pragma unroll
        for (int j = 0; j < 4; ++j) acc[i][j] = (f32x4){0.f, 0.f, 0.f, 0.f};

    for (int kt = 0; kt < EMB; kt += 64) {
        if (kt) __syncthreads();
#pragma unroll
        for (int i = 0; i < 4; ++i) {
            __hip_bfloat16* l = &As[0][0] + i * 2048 + tid * 8;
            __builtin_amdgcn_global_load_lds(
                (const __attribute__((address_space(1))) void*)(gA + (size_t)i * 32 * EMB + kt),
                (__attribute__((address_space(3))) void*)l, 16, 0, 0);
        }
#pragma unroll
        for (int i = 0; i < 4; ++i) {
            __hip_bfloat16* l = &Bs[0][0] + i * 2048 + tid * 8;
            __builtin_amdgcn_global_load_lds(
                (const __attribute__((address_space(1))) void*)(gB + (size_t)i * 32 * EMB + kt),
                (__attribute__((address_space(3))) void*)l, 16, 0, 0);
        }
        asm volatile("s_waitcnt vmcnt(0)" ::: "memory");
        __syncthreads();

#pragma unroll
        for (int kk = 0; kk < 2; ++kk) {
            bf16x8 af[4], bfr[4];
            int sg = kk * 4 + (lane >> 4);
#pragma unroll
            for (int mi = 0; mi < 4; ++mi) {
                int row = wr * 64 + mi * 16 + (lane & 15);
                int sl  = sg ^ (row & 7);
                af[mi] = *reinterpret_cast<const bf16x8*>(&As[row][sl * 8]);
            }
#pragma unroll
            for (int ni = 0; ni < 4; ++ni) {
                int row = wc * 64 + ni * 16 + (lane & 15);
                int sl  = sg ^ (row & 7);
                bfr[ni] = *reinterpret_cast<const bf16x8*>(&Bs[row][sl * 8]);
            }
#pragma unroll
            for (int mi = 0; mi < 4; ++mi)
#pragma unroll
                for (int ni = 0; ni < 4; ++ni)
                    acc[mi][ni] = __builtin_amdgcn_mfma_f32_16x16x32_bf16(
                        af[mi], bfr[ni], acc[mi][ni], 0, 0, 0);
        }
    }

    int rg = lane >> 4, cli = lane & 15;
#pragma unroll
    for (int mi = 0; mi < 4; ++mi)
#pragma unroll
        for (int j = 0; j < 4; ++j) {
            int m = mbase + wr * 64 + mi * 16 + rg * 4 + j;
            if (m < M) {
#pragma unroll
                for (int ni = 0; ni < 4; ++ni)
                    C[(size_t)m * EMB + nbase + wc * 64 + ni * 16 + cli] =
                        __float2bfloat16(acc[mi][ni][j]);
            }
        }
}

// ---------------- MFMA flash attention v2: XOR-swizzled LDS, no-max softmax
// block per (b,h), 4 waves x 48 q-rows
__global__ __launch_bounds__(256) void attn_mfma_kernel(
    const __hip_bfloat16* __restrict__ Qb, const __hip_bfloat16* __restrict__ Kb,
    const __hip_bfloat16* __restrict__ Vb, __hip_bfloat16* __restrict__ O)
{
    int bh = blockIdx.x;
    int b = bh >> 3, h = bh & 7;
    const size_t base = (size_t)b * SEQ * EMB + (size_t)h * HD;

    // K2: row = t>>1, slot = (t&1)*4 + d/8, phys = slot^(row&7)
    __shared__ short K2[96][64];          // 12288 B
    // Vt: row = d, slot = t>>3, phys = slot^(d&7)
    __shared__ short Vt[32][256];         // 16384 B
    // P2: per wave, row = q, slot = ts>>3 (ts in half), phys = slot^(q&7)
    __shared__ short P2[4][16][128];      // 16384 B

    int tid  = threadIdx.x;
    int wave = tid >> 6, lane = tid & 63;
    int cl = lane & 15, rg = lane >> 4;

    // ---- stage K (swizzled b128) + V transposed (rotated scalar scatter)
    for (int u = tid; u < 192 * 4; u += 256) {
        int t = u >> 2, d0 = (u & 3) << 3;
        uint4 kv = make_uint4(0, 0, 0, 0), vv = make_uint4(0, 0, 0, 0);
        if (t < SEQ) {
            kv = *reinterpret_cast<const uint4*>(&Kb[base + (size_t)t * EMB + d0]);
            vv = *reinterpret_cast<const uint4*>(&Vb[base + (size_t)t * EMB + d0]);
        }
        int krow = t >> 1;
        int kphy = (((t & 1) * 4 + (d0 >> 3)) ^ (krow & 7));
        *reinterpret_cast<uint4*>(&K2[krow][kphy * 8]) = kv;

        const unsigned short* pv = reinterpret_cast<const unsigned short*>(&vv);
        int slot = t >> 3;
        int rot  = (u & 3) * 2;
#pragma unroll
        for (int k = 0; k < 8; ++k) {
            int i = (k + rot) & 7;          // d&7 varies across lanes per instr
            int d = d0 + i;
            Vt[d][(slot ^ i) * 8 + (t & 7)] = (short)pv[i];
        }
    }
    __syncthreads();

    // scale/SEQ * log2(e), for exp2
    const float csw2 = (0.0625f / (float)SEQ) * 1.4426950408889634f;

    for (int qt = 0; qt < 3; ++qt) {
        int qbase = wave * 48 + qt * 16;

        bf16x8 aq = {};
        int sq = qbase + cl;
        if (sq < SEQ)
            aq = *reinterpret_cast<const bf16x8*>(&Qb[base + (size_t)sq * EMB + rg * 8]);

        f32x4 o0 = {0.f, 0.f, 0.f, 0.f}, o1 = {0.f, 0.f, 0.f, 0.f};
        float lrow[4] = {0.f, 0.f, 0.f, 0.f};
        float sf0 = (float)(qbase + rg * 4);

        for (int hh = 0; hh < 2; ++hh) {
            // ---- QK^T for this 96-t half
            f32x4 st[6];
#pragma unroll
            for (int tl = 0; tl < 6; ++tl) {
                int t   = (hh * 6 + tl) * 16 + cl;
                int kr  = t >> 1;
                int kph = (((t & 1) * 4 + rg) ^ (kr & 7));
                bf16x8 kf = *reinterpret_cast<const bf16x8*>(&K2[kr][kph * 8]);
                st[tl] = __builtin_amdgcn_mfma_f32_16x16x32_bf16(
                    aq, kf, (f32x4){0.f, 0.f, 0.f, 0.f}, 0, 0, 0);
            }

            // ---- fused mask+exp+sum+P-write (no max pass: |logit| <= ~0.2)
#pragma unroll
            for (int tl = 0; tl < 6; ++tl) {
                int t    = hh * 96 + tl * 16 + cl;
                float tf = (float)t;
#pragma unroll
                for (int j = 0; j < 4; ++j) {
                    float w   = fabsf((sf0 + (float)j) - tf) * csw2;
                    float p   = exp2f(st[tl][j] * w);
                    if (t >= SEQ) p = 0.f;
                    lrow[j] += p;
                    int q    = rg * 4 + j;
                    int phys = ((tl * 2 + (cl >> 3)) ^ (q & 7));
                    P2[wave][q][phys * 8 + (cl & 7)] = f2bf(p);
                }
            }
            asm volatile("s_waitcnt lgkmcnt(0)" ::: "memory"); // wave-local wr->rd

            // ---- PV for this half: 3 t-chunks of 32
#pragma unroll
            for (int tcl = 0; tcl < 3; ++tcl) {
                int pph = ((tcl * 4 + rg) ^ (cl & 7));
                bf16x8 pa = *reinterpret_cast<const bf16x8*>(&P2[wave][cl][pph * 8]);
                int vsl = ((hh * 3 + tcl) * 4 + rg);
                int vp0 = (vsl ^ (cl & 7));
                bf16x8 b0 = *reinterpret_cast<const bf16x8*>(&Vt[cl][vp0 * 8]);
                bf16x8 b1 = *reinterpret_cast<const bf16x8*>(&Vt[cl + 16][vp0 * 8]);
                o0 = __builtin_amdgcn_mfma_f32_16x16x32_bf16(pa, b0, o0, 0, 0, 0);
                o1 = __builtin_amdgcn_mfma_f32_16x16x32_bf16(pa, b1, o1, 0, 0, 0);
            }
            asm volatile("s_waitcnt lgkmcnt(0)" ::: "memory"); // reads done before P reuse
        }

        // ---- FIX (round 5 bug): reduce row sum across the 16-lane cl group
#pragma unroll
        for (int j = 0; j < 4; ++j) {
            lrow[j] += __shfl_xor(lrow[j], 1);
            lrow[j] += __shfl_xor(lrow[j], 2);
            lrow[j] += __shfl_xor(lrow[j], 4);
            lrow[j] += __shfl_xor(lrow[j], 8);
        }

        // ---- store bf16 (divide by full row sum)
#pragma unroll
        for (int j = 0; j < 4; ++j) {
            int s = qbase + rg * 4 + j;
            if (s < SEQ) {
                float rl = 1.0f / lrow[j];
                __hip_bfloat16* op = &O[base + (size_t)s * EMB];
                op[cl]      = __float2bfloat16(o0[j] * rl);
                op[16 + cl] = __float2bfloat16(o1[j] * rl);
            }
        }
    }
}

// ---------------- row LayerNorm + PE: wave-per-row, 4 rows/block, bf16 io
__global__ __launch_bounds__(256) void ln_pe4_kernel(
    const __hip_bfloat16* __restrict__ X, const float* __restrict__ g,
    const float* __restrict__ bb, const float* __restrict__ pe,
    __hip_bfloat16* __restrict__ Xb, int M)
{
    int r = blockIdx.x * 4 + (threadIdx.x >> 6);
    if (r >= M) return;
    int lane = threadIdx.x & 63;
    int s = r % SEQ;
    int c0 = lane * 4;

    uint2 raw = *reinterpret_cast<const uint2*>(&X[(size_t)r * EMB + c0]);
    float v[4];
    v[0] = __uint_as_float((raw.x & 0xffffu) << 16);
    v[1] = __uint_as_float(raw.x & 0xffff0000u);
    v[2] = __uint_as_float((raw.y & 0xffffu) << 16);
    v[3] = __uint_as_float(raw.y & 0xffff0000u);

    float sum = v[0] + v[1] + v[2] + v[3];
    float sq  = v[0]*v[0] + v[1]*v[1] + v[2]*v[2] + v[3]*v[3];
#pragma unroll
    for (int off = 32; off > 0; off >>= 1) {
        sum += __shfl_xor(sum, off);
        sq  += __shfl_xor(sq,  off);
    }
    float mu  = sum * (1.0f / EMB);
    float var = sq * (1.0f / EMB) - mu * mu;
    float is  = rsqrtf(var + EPSV);

    float4 gv = *reinterpret_cast<const float4*>(&g[c0]);
    float4 bv = *reinterpret_cast<const float4*>(&bb[c0]);
    float4 pv = *reinterpret_cast<const float4*>(&pe[s * EMB + c0]);
    float y0 = (v[0] - mu) * is * gv.x + bv.x + pv.x;
    float y1 = (v[1] - mu) * is * gv.y + bv.y + pv.y;
    float y2 = (v[2] - mu) * is * gv.z + bv.z + pv.z;
    float y3 = (v[3] - mu) * is * gv.w + bv.w + pv.w;

    uint2 o;
    o.x = (unsigned short)f2bf(y0) | ((unsigned)(unsigned short)f2bf(y1) << 16);
    o.y = (unsigned short)f2bf(y2) | ((unsigned)(unsigned short)f2bf(y3) << 16);
    *reinterpret_cast<uint2*>(&Xb[(size_t)r * EMB + c0]) = o;
}

// ------- fused: LN(lnA2) -> LN(ln2) -> mean-pool over SEQ -> FC[10]
__global__ __launch_bounds__(256) void lnfc_kernel(
    const __hip_bfloat16* __restrict__ X,
    const float* __restrict__ g1, const float* __restrict__ b1,
    const float* __restrict__ g2, const float* __restrict__ b2,
    const float* __restrict__ ow, const float* __restrict__ ob,
    float* __restrict__ out)
{
    int b    = blockIdx.x;
    int tid  = threadIdx.x;
    int wave = tid >> 6, lane = tid & 63;

    float g1v[4], b1v[4], g2v[4], b2v[4], pooled[4];
#pragma unroll
    for (int j = 0; j < 4; ++j) {
        int c = lane + 64 * j;
        g1v[j] = g1[c]; b1v[j] = b1[c];
        g2v[j] = g2[c]; b2v[j] = b2[c];
        pooled[j] = 0.f;
    }

    for (int s = wave; s < SEQ; s += 4) {
        const __hip_bfloat16* row = &X[((size_t)b * SEQ + s) * EMB];
        float v[4];
#pragma unroll
        for (int j = 0; j < 4; ++j) v[j] = __bfloat162float(row[lane + 64 * j]);

        float sum = v[0] + v[1] + v[2] + v[3];
        float sq  = v[0]*v[0] + v[1]*v[1] + v[2]*v[2] + v[3]*v[3];
#pragma unroll
        for (int off = 32; off > 0; off >>= 1) {
            sum += __shfl_xor(sum, off);
            sq  += __shfl_xor(sq,  off);
        }
        float mu  = sum * (1.0f / EMB);
        float var = sq * (1.0f / EMB) - mu * mu;
        float is  = rsqrtf(var + EPSV);
        float y[4];
#pragma unroll
        for (int j = 0; j < 4; ++j) y[j] = (v[j] - mu) * is * g1v[j] + b1v[j];

        sum = y[0] + y[1] + y[2] + y[3];
        sq  = y[0]*y[0] + y[1]*y[1] + y[2]*y[2] + y[3]*y[3];
#pragma unroll
        for (int off = 32; off > 0; off >>= 1) {
            sum += __shfl_xor(sum, off);
            sq  += __shfl_xor(sq,  off);
        }
        mu  = sum * (1.0f / EMB);
        var = sq * (1.0f / EMB) - mu * mu;
        is  = rsqrtf(var + EPSV);
#pragma unroll
        for (int j = 0; j < 4; ++j) pooled[j] += (y[j] - mu) * is * g2v[j] + b2v[j];
    }

    __shared__ float pp[4][EMB];
#pragma unroll
    for (int j = 0; j < 4; ++j) pp[wave][lane + 64 * j] = pooled[j];
    __syncthreads();
    __shared__ float pool[EMB];
    pool[tid] = (pp[0][tid] + pp[1][tid] + pp[2][tid] + pp[3][tid]) * (1.0f / (float)SEQ);
    __syncthreads();
    if (tid < 10) {
        float o = ob[tid];
        for (int k = 0; k < EMB; ++k) o += pool[k] * ow[tid * EMB + k];
        out[b * 10 + tid] = o;
    }
}

// ---------------------------------------------------------------- launch
extern "C" void kernel_launch(void* const* d_in, const int* in_sizes, int n_in,
                              void* d_out, int out_size, void* d_ws, size_t ws_size,
                              hipStream_t stream)
{
    const float* x      = (const float*)d_in[0];
    const float* conv_w = (const float*)d_in[1];
    const float* conv_b = (const float*)d_in[2];
    const float* bn_g   = (const float*)d_in[3];
    const float* bn_b   = (const float*)d_in[4];
    const float* bn_m   = (const float*)d_in[5];
    const float* bn_v   = (const float*)d_in[6];
    const float* wq1    = (const float*)d_in[7];
    const float* wk1    = (const float*)d_in[8];
    const float* wv1    = (const float*)d_in[9];
    const float* lnA1_g = (const float*)d_in[10];
    const float* lnA1_b = (const float*)d_in[11];
    const float* wq2    = (const float*)d_in[12];
    const float* wk2    = (const float*)d_in[13];
    const float* wv2    = (const float*)d_in[14];
    const float* lnA2_g = (const float*)d_in[15];
    const float* lnA2_b = (const float*)d_in[16];
    const float* ln2_g  = (const float*)d_in[17];
    const float* ln2_b  = (const float*)d_in[18];
    const float* out_w  = (const float*)d_in[19];
    const float* out_b  = (const float*)d_in[20];
    float* out = (float*)d_out;

    const size_t peN = (size_t)SEQ * EMB;
    const size_t wN  = (size_t)EMB * EMB;

    int chunk = B_TOT;
    while (chunk > 1) {
        size_t M    = (size_t)chunk * SEQ;
        size_t Mpad = (M + 127) / 128 * 128;
        size_t need = peN * 4 + 6 * wN * 2 + (Mpad + 4 * M) * EMB * 2;
        if (need <= ws_size) break;
        chunk >>= 1;
    }
    size_t M    = (size_t)chunk * SEQ;
    size_t Mpad = (M + 127) / 128 * 128;

    float*          pe = (float*)d_ws;
    __hip_bfloat16* Wb = (__hip_bfloat16*)(pe + peN);
    __hip_bfloat16* Xb = Wb + 6 * wN;
    __hip_bfloat16* Ob = Xb + Mpad * EMB;
    __hip_bfloat16* Qb = Ob + M * EMB;
    __hip_bfloat16* Kb = Qb + M * EMB;
    __hip_bfloat16* Vb = Kb + M * EMB;

    pe_kernel<<<(SEQ * EMB + 255) / 256, 256, 0, stream>>>(pe);
    {
        dim3 cg((unsigned)(wN / 1024), 6);
        cvt6_kernel<<<cg, 256, 0, stream>>>(wq1, wk1, wv1, wq2, wk2, wv2, Wb, (int)wN);
    }

    for (int b0 = 0; b0 < B_TOT; b0 += chunk) {
        int Bc = chunk;
        int Mi = Bc * SEQ;
        dim3 ggrid((unsigned)(Mpad / 128), 6);

        embed_kernel<<<Bc * SEQ, 256, 0, stream>>>(
            x + (size_t)b0 * LIN, conv_w, conv_b, bn_g, bn_b, bn_m, bn_v, pe, Xb);

        // --- attention block 1 ---
        gemm_qkv_mfma<<<ggrid, 256, 0, stream>>>(Xb, Wb, Qb, Kb, Vb, Mi);
        attn_mfma_kernel<<<Bc * HEADS, 256, 0, stream>>>(Qb, Kb, Vb, Ob);
        ln_pe4_kernel<<<(Mi + 3) / 4, 256, 0, stream>>>(Ob, lnA1_g, lnA1_b, pe, Xb, Mi);

        // --- attention block 2 ---
        gemm_qkv_mfma<<<ggrid, 256, 0, stream>>>(Xb, Wb + 3 * wN, Qb, Kb, Vb, Mi);
        attn_mfma_kernel<<<Bc * HEADS, 256, 0, stream>>>(Qb, Kb, Vb, Ob);
        lnfc_kernel<<<Bc, 256, 0, stream>>>(Ob, lnA2_g, lnA2_b, ln2_g, ln2_b,
                                            out_w, out_b, out + (size_t)b0 * 10);
    }
}

// Round 7
// 443.967 us; speedup vs baseline: 5.2657x; 1.0425x over previous
//
#include <hip/hip_runtime.h>
#include <hip/hip_bf16.h>
#include <math.h>

#define B_TOT 512
#define SEQ   179
#define EMB   256
#define HEADS 8
#define HD    32
#define LIN   720
#define EPSV  1e-5f

typedef __attribute__((ext_vector_type(8))) short bf16x8;
typedef __attribute__((ext_vector_type(4))) float f32x4;

__device__ __forceinline__ short f2bf(float f) {          // RNE f32->bf16 bits
    unsigned u = __float_as_uint(f);
    return (short)((u + 0x7fff + ((u >> 16) & 1)) >> 16);
}
__device__ __forceinline__ unsigned cvt_pk_bf16(float lo, float hi) {
    unsigned r;
    asm("v_cvt_pk_bf16_f32 %0, %1, %2" : "=v"(r) : "v"(lo), "v"(hi));
    return r;
}

// ---------------------------------------------------------------- PE table
__global__ void pe_kernel(float* __restrict__ pe) {
    int idx = blockIdx.x * 256 + threadIdx.x;
    if (idx >= SEQ * EMB) return;
    int s = idx / EMB, e = idx % EMB;
    int i = e >> 1;
    float dv  = expf((float)(2 * i) * (-9.210340371976184f / (float)EMB));
    float ang = (float)s * dv * ((float)EMB / (float)SEQ);
    pe[idx] = (e & 1) ? cosf(ang) : sinf(ang);
}

// ------------------------------------- f32 -> bf16 convert, 6 weights at once
__global__ void cvt6_kernel(const float* __restrict__ s0, const float* __restrict__ s1,
                            const float* __restrict__ s2, const float* __restrict__ s3,
                            const float* __restrict__ s4, const float* __restrict__ s5,
                            __hip_bfloat16* __restrict__ dst, int n) {
    int w = blockIdx.y;
    const float* src = (w == 0) ? s0 : (w == 1) ? s1 : (w == 2) ? s2
                     : (w == 3) ? s3 : (w == 4) ? s4 : s5;
    __hip_bfloat16* d = dst + (size_t)w * n;
    int i = (blockIdx.x * 256 + threadIdx.x) * 4;
    if (i < n) {
        float4 v = *reinterpret_cast<const float4*>(&src[i]);
        d[i + 0] = __float2bfloat16(v.x);
        d[i + 1] = __float2bfloat16(v.y);
        d[i + 2] = __float2bfloat16(v.z);
        d[i + 3] = __float2bfloat16(v.w);
    }
}

// ------------------------ conv(stride4,K8) + BN + ReLU + PE -> bf16 X
__global__ __launch_bounds__(256) void embed_kernel(
    const float* __restrict__ x, const float* __restrict__ cw,
    const float* __restrict__ cb, const float* __restrict__ g,
    const float* __restrict__ bb, const float* __restrict__ mean,
    const float* __restrict__ var, const float* __restrict__ pe,
    __hip_bfloat16* __restrict__ Xb)
{
    int bs = blockIdx.x;
    int b  = bs / SEQ, s = bs % SEQ;
    int e  = threadIdx.x;
    __shared__ float xin[8];
    if (threadIdx.x < 8) xin[threadIdx.x] = x[(size_t)b * LIN + s * 4 + threadIdx.x];
    __syncthreads();
    float acc = cb[e];
#pragma unroll
    for (int j = 0; j < 8; ++j) acc += xin[j] * cw[e * 8 + j];
    acc = (acc - mean[e]) * (g[e] * rsqrtf(var[e] + EPSV)) + bb[e];
    acc = fmaxf(acc, 0.f);
    Xb[(size_t)bs * EMB + e] = __float2bfloat16(acc + pe[s * EMB + e]);
}

// ---------------- MFMA bf16 GEMM: C[m,n] = sum_k A[m,k] * W[n,k], C in bf16
__global__ __launch_bounds__(256) void gemm_qkv_mfma(
    const __hip_bfloat16* __restrict__ A,    // [Mpad][256]
    const __hip_bfloat16* __restrict__ Wset, // [3][256][256]
    __hip_bfloat16* __restrict__ Q, __hip_bfloat16* __restrict__ K,
    __hip_bfloat16* __restrict__ V, int M)
{
    int by = blockIdx.y;                       // 0..5
    int wsel = by >> 1;
    const __hip_bfloat16* W = Wset + (size_t)wsel * EMB * EMB;
    __hip_bfloat16* C = (wsel == 0) ? Q : (wsel == 1 ? K : V);
    int nbase = (by & 1) * 128;
    int mbase = blockIdx.x * 128;

    __shared__ __hip_bfloat16 As[128][64];
    __shared__ __hip_bfloat16 Bs[128][64];

    int tid  = threadIdx.x;
    int wave = tid >> 6, lane = tid & 63;
    int wr = wave >> 1, wc = wave & 1;

    int r0   = tid >> 3;
    int srcs = (tid & 7) ^ (r0 & 7);
    const __hip_bfloat16* gA = A + (size_t)(mbase + r0) * EMB + srcs * 8;
    const __hip_bfloat16* gB = W + (size_t)(nbase + r0) * EMB + srcs * 8;

    f32x4 acc[4][4];
#pragma unroll
    for (int i = 0; i < 4; ++i)
#pragma unroll
        for (int j = 0; j < 4; ++j) acc[i][j] = (f32x4){0.f, 0.f, 0.f, 0.f};

    for (int kt = 0; kt < EMB; kt += 64) {
        if (kt) __syncthreads();
#pragma unroll
        for (int i = 0; i < 4; ++i) {
            __hip_bfloat16* l = &As[0][0] + i * 2048 + tid * 8;
            __builtin_amdgcn_global_load_lds(
                (const __attribute__((address_space(1))) void*)(gA + (size_t)i * 32 * EMB + kt),
                (__attribute__((address_space(3))) void*)l, 16, 0, 0);
        }
#pragma unroll
        for (int i = 0; i < 4; ++i) {
            __hip_bfloat16* l = &Bs[0][0] + i * 2048 + tid * 8;
            __builtin_amdgcn_global_load_lds(
                (const __attribute__((address_space(1))) void*)(gB + (size_t)i * 32 * EMB + kt),
                (__attribute__((address_space(3))) void*)l, 16, 0, 0);
        }
        asm volatile("s_waitcnt vmcnt(0)" ::: "memory");
        __syncthreads();

#pragma unroll
        for (int kk = 0; kk < 2; ++kk) {
            bf16x8 af[4], bfr[4];
            int sg = kk * 4 + (lane >> 4);
#pragma unroll
            for (int mi = 0; mi < 4; ++mi) {
                int row = wr * 64 + mi * 16 + (lane & 15);
                int sl  = sg ^ (row & 7);
                af[mi] = *reinterpret_cast<const bf16x8*>(&As[row][sl * 8]);
            }
#pragma unroll
            for (int ni = 0; ni < 4; ++ni) {
                int row = wc * 64 + ni * 16 + (lane & 15);
                int sl  = sg ^ (row & 7);
                bfr[ni] = *reinterpret_cast<const bf16x8*>(&Bs[row][sl * 8]);
            }
#pragma unroll
            for (int mi = 0; mi < 4; ++mi)
#pragma unroll
                for (int ni = 0; ni < 4; ++ni)
                    acc[mi][ni] = __builtin_amdgcn_mfma_f32_16x16x32_bf16(
                        af[mi], bfr[ni], acc[mi][ni], 0, 0, 0);
        }
    }

    int rg = lane >> 4, cli = lane & 15;
#pragma unroll
    for (int mi = 0; mi < 4; ++mi)
#pragma unroll
        for (int j = 0; j < 4; ++j) {
            int m = mbase + wr * 64 + mi * 16 + rg * 4 + j;
            if (m < M) {
#pragma unroll
                for (int ni = 0; ni < 4; ++ni)
                    C[(size_t)m * EMB + nbase + wc * 64 + ni * 16 + cli] =
                        __float2bfloat16(acc[mi][ni][j]);
            }
        }
}

// ---------------- MFMA flash attention v3: swapped QK^T (q lane-local),
// cvt_pk packed P writes, scalar lrow. Block per (b,h), 4 waves x 48 q-rows.
__global__ __launch_bounds__(256) void attn_mfma_kernel(
    const __hip_bfloat16* __restrict__ Qb, const __hip_bfloat16* __restrict__ Kb,
    const __hip_bfloat16* __restrict__ Vb, __hip_bfloat16* __restrict__ O)
{
    int bh = blockIdx.x;
    int b = bh >> 3, h = bh & 7;
    const size_t base = (size_t)b * SEQ * EMB + (size_t)h * HD;

    // K2: row = t>>1, slot = (t&1)*4 + d/8, phys = slot^(row&7)
    __shared__ short K2[96][64];          // 12288 B
    // Vt: row = d, slot = t>>3, phys = slot^(d&7)
    __shared__ short Vt[32][256];         // 16384 B
    // P2: per wave, row = q(16), t in [0,96), stride 104 (13x16B -> ~2-way)
    __shared__ short P2[4][16][104];      // 13312 B

    int tid  = threadIdx.x;
    int wave = tid >> 6, lane = tid & 63;
    int cl = lane & 15, rg = lane >> 4;

    // ---- stage K (swizzled b128) + V transposed (rotated scalar scatter)
    for (int u = tid; u < 192 * 4; u += 256) {
        int t = u >> 2, d0 = (u & 3) << 3;
        uint4 kv = make_uint4(0, 0, 0, 0), vv = make_uint4(0, 0, 0, 0);
        if (t < SEQ) {
            kv = *reinterpret_cast<const uint4*>(&Kb[base + (size_t)t * EMB + d0]);
            vv = *reinterpret_cast<const uint4*>(&Vb[base + (size_t)t * EMB + d0]);
        }
        int krow = t >> 1;
        int kphy = (((t & 1) * 4 + (d0 >> 3)) ^ (krow & 7));
        *reinterpret_cast<uint4*>(&K2[krow][kphy * 8]) = kv;

        const unsigned short* pv = reinterpret_cast<const unsigned short*>(&vv);
        int slot = t >> 3;
        int rot  = (u & 3) * 2;
#pragma unroll
        for (int k = 0; k < 8; ++k) {
            int i = (k + rot) & 7;          // d&7 varies across lanes per instr
            int d = d0 + i;
            Vt[d][(slot ^ i) * 8 + (t & 7)] = (short)pv[i];
        }
    }
    __syncthreads();

    // scale/SEQ * log2(e), for exp2
    const float csw2 = (0.0625f / (float)SEQ) * 1.4426950408889634f;

    for (int qt = 0; qt < 3; ++qt) {
        int qbase = wave * 48 + qt * 16;

        // Q fragment (B operand): col = cl -> q = qbase+cl, k(d) = rg*8..+7
        bf16x8 aq = {};
        int sq = qbase + cl;
        if (sq < SEQ)
            aq = *reinterpret_cast<const bf16x8*>(&Qb[base + (size_t)sq * EMB + rg * 8]);
        float sf = (float)sq;

        f32x4 o0 = {0.f, 0.f, 0.f, 0.f}, o1 = {0.f, 0.f, 0.f, 0.f};
        float lrow = 0.f;                 // row-sum for q = cl (partial over rg)

        for (int hh = 0; hh < 2; ++hh) {
            // ---- K^T Q: swapped operands -> C[row=t_loc][col=q_loc]
            // per lane: q = cl (fixed), t = tile*16 + rg*4 + j
            f32x4 st[6];
#pragma unroll
            for (int tl = 0; tl < 6; ++tl) {
                int t   = (hh * 6 + tl) * 16 + cl;   // A-frag row index uses cl
                int kr  = t >> 1;
                int kph = (((t & 1) * 4 + rg) ^ (kr & 7));
                bf16x8 kf = *reinterpret_cast<const bf16x8*>(&K2[kr][kph * 8]);
                st[tl] = __builtin_amdgcn_mfma_f32_16x16x32_bf16(
                    kf, aq, (f32x4){0.f, 0.f, 0.f, 0.f}, 0, 0, 0);
            }

            // ---- fused weight+exp+sum + packed P write (4 consecutive t/lane)
#pragma unroll
            for (int tl = 0; tl < 6; ++tl) {
                int tb = hh * 96 + tl * 16 + rg * 4;
                float d0 = sf - (float)tb;
                float p[4];
#pragma unroll
                for (int j = 0; j < 4; ++j)
                    p[j] = exp2f(st[tl][j] * (fabsf(d0 - (float)j) * csw2));
                if (hh == 1 && tl == 5) {            // only tile containing t>=SEQ
#pragma unroll
                    for (int j = 0; j < 4; ++j)
                        if (tb + j >= SEQ) p[j] = 0.f;
                }
                lrow += (p[0] + p[1]) + (p[2] + p[3]);
                uint2 pk;
                pk.x = cvt_pk_bf16(p[0], p[1]);
                pk.y = cvt_pk_bf16(p[2], p[3]);
                *reinterpret_cast<uint2*>(&P2[wave][cl][tl * 16 + rg * 4]) = pk;
            }
            asm volatile("s_waitcnt lgkmcnt(0)" ::: "memory"); // wave-local wr->rd

            // ---- PV for this half: 3 t-chunks of 32
#pragma unroll
            for (int tcl = 0; tcl < 3; ++tcl) {
                bf16x8 pa = *reinterpret_cast<const bf16x8*>(&P2[wave][cl][tcl * 32 + rg * 8]);
                int vsl = ((hh * 3 + tcl) * 4 + rg);
                int vp0 = (vsl ^ (cl & 7));
                bf16x8 b0 = *reinterpret_cast<const bf16x8*>(&Vt[cl][vp0 * 8]);
                bf16x8 b1 = *reinterpret_cast<const bf16x8*>(&Vt[cl + 16][vp0 * 8]);
                o0 = __builtin_amdgcn_mfma_f32_16x16x32_bf16(pa, b0, o0, 0, 0, 0);
                o1 = __builtin_amdgcn_mfma_f32_16x16x32_bf16(pa, b1, o1, 0, 0, 0);
            }
            asm volatile("s_waitcnt lgkmcnt(0)" ::: "memory"); // reads done before P reuse
        }

        // ---- full row sum for q=cl: reduce across the 4 rg-groups
        lrow += __shfl_xor(lrow, 16);
        lrow += __shfl_xor(lrow, 32);

        // ---- store bf16; row q = qbase + rg*4 + j needs lrow from lane rg*4+j
#pragma unroll
        for (int j = 0; j < 4; ++j) {
            int s = qbase + rg * 4 + j;
            if (s < SEQ) {
                float rl = 1.0f / __shfl(lrow, rg * 4 + j);
                __hip_bfloat16* op = &O[base + (size_t)s * EMB];
                op[cl]      = __float2bfloat16(o0[j] * rl);
                op[16 + cl] = __float2bfloat16(o1[j] * rl);
            }
        }
    }
}

// ---------------- row LayerNorm + PE: wave-per-row, 4 rows/block, bf16 io
__global__ __launch_bounds__(256) void ln_pe4_kernel(
    const __hip_bfloat16* __restrict__ X, const float* __restrict__ g,
    const float* __restrict__ bb, const float* __restrict__ pe,
    __hip_bfloat16* __restrict__ Xb, int M)
{
    int r = blockIdx.x * 4 + (threadIdx.x >> 6);
    if (r >= M) return;
    int lane = threadIdx.x & 63;
    int s = r % SEQ;
    int c0 = lane * 4;

    uint2 raw = *reinterpret_cast<const uint2*>(&X[(size_t)r * EMB + c0]);
    float v[4];
    v[0] = __uint_as_float((raw.x & 0xffffu) << 16);
    v[1] = __uint_as_float(raw.x & 0xffff0000u);
    v[2] = __uint_as_float((raw.y & 0xffffu) << 16);
    v[3] = __uint_as_float(raw.y & 0xffff0000u);

    float sum = v[0] + v[1] + v[2] + v[3];
    float sq  = v[0]*v[0] + v[1]*v[1] + v[2]*v[2] + v[3]*v[3];
#pragma unroll
    for (int off = 32; off > 0; off >>= 1) {
        sum += __shfl_xor(sum, off);
        sq  += __shfl_xor(sq,  off);
    }
    float mu  = sum * (1.0f / EMB);
    float var = sq * (1.0f / EMB) - mu * mu;
    float is  = rsqrtf(var + EPSV);

    float4 gv = *reinterpret_cast<const float4*>(&g[c0]);
    float4 bv = *reinterpret_cast<const float4*>(&bb[c0]);
    float4 pv = *reinterpret_cast<const float4*>(&pe[s * EMB + c0]);
    float y0 = (v[0] - mu) * is * gv.x + bv.x + pv.x;
    float y1 = (v[1] - mu) * is * gv.y + bv.y + pv.y;
    float y2 = (v[2] - mu) * is * gv.z + bv.z + pv.z;
    float y3 = (v[3] - mu) * is * gv.w + bv.w + pv.w;

    uint2 o;
    o.x = (unsigned short)f2bf(y0) | ((unsigned)(unsigned short)f2bf(y1) << 16);
    o.y = (unsigned short)f2bf(y2) | ((unsigned)(unsigned short)f2bf(y3) << 16);
    *reinterpret_cast<uint2*>(&Xb[(size_t)r * EMB + c0]) = o;
}

// ------- fused: LN(lnA2) -> LN(ln2) -> mean-pool over SEQ -> FC[10]
__global__ __launch_bounds__(256) void lnfc_kernel(
    const __hip_bfloat16* __restrict__ X,
    const float* __restrict__ g1, const float* __restrict__ b1,
    const float* __restrict__ g2, const float* __restrict__ b2,
    const float* __restrict__ ow, const float* __restrict__ ob,
    float* __restrict__ out)
{
    int b    = blockIdx.x;
    int tid  = threadIdx.x;
    int wave = tid >> 6, lane = tid & 63;

    float g1v[4], b1v[4], g2v[4], b2v[4], pooled[4];
#pragma unroll
    for (int j = 0; j < 4; ++j) {
        int c = lane + 64 * j;
        g1v[j] = g1[c]; b1v[j] = b1[c];
        g2v[j] = g2[c]; b2v[j] = b2[c];
        pooled[j] = 0.f;
    }

    for (int s = wave; s < SEQ; s += 4) {
        const __hip_bfloat16* row = &X[((size_t)b * SEQ + s) * EMB];
        float v[4];
#pragma unroll
        for (int j = 0; j < 4; ++j) v[j] = __bfloat162float(row[lane + 64 * j]);

        float sum = v[0] + v[1] + v[2] + v[3];
        float sq  = v[0]*v[0] + v[1]*v[1] + v[2]*v[2] + v[3]*v[3];
#pragma unroll
        for (int off = 32; off > 0; off >>= 1) {
            sum += __shfl_xor(sum, off);
            sq  += __shfl_xor(sq,  off);
        }
        float mu  = sum * (1.0f / EMB);
        float var = sq * (1.0f / EMB) - mu * mu;
        float is  = rsqrtf(var + EPSV);
        float y[4];
#pragma unroll
        for (int j = 0; j < 4; ++j) y[j] = (v[j] - mu) * is * g1v[j] + b1v[j];

        sum = y[0] + y[1] + y[2] + y[3];
        sq  = y[0]*y[0] + y[1]*y[1] + y[2]*y[2] + y[3]*y[3];
#pragma unroll
        for (int off = 32; off > 0; off >>= 1) {
            sum += __shfl_xor(sum, off);
            sq  += __shfl_xor(sq,  off);
        }
        mu  = sum * (1.0f / EMB);
        var = sq * (1.0f / EMB) - mu * mu;
        is  = rsqrtf(var + EPSV);
#pragma unroll
        for (int j = 0; j < 4; ++j) pooled[j] += (y[j] - mu) * is * g2v[j] + b2v[j];
    }

    __shared__ float pp[4][EMB];
#pragma unroll
    for (int j = 0; j < 4; ++j) pp[wave][lane + 64 * j] = pooled[j];
    __syncthreads();
    __shared__ float pool[EMB];
    pool[tid] = (pp[0][tid] + pp[1][tid] + pp[2][tid] + pp[3][tid]) * (1.0f / (float)SEQ);
    __syncthreads();
    if (tid < 10) {
        float o = ob[tid];
        for (int k = 0; k < EMB; ++k) o += pool[k] * ow[tid * EMB + k];
        out[b * 10 + tid] = o;
    }
}

// ---------------------------------------------------------------- launch
extern "C" void kernel_launch(void* const* d_in, const int* in_sizes, int n_in,
                              void* d_out, int out_size, void* d_ws, size_t ws_size,
                              hipStream_t stream)
{
    const float* x      = (const float*)d_in[0];
    const float* conv_w = (const float*)d_in[1];
    const float* conv_b = (const float*)d_in[2];
    const float* bn_g   = (const float*)d_in[3];
    const float* bn_b   = (const float*)d_in[4];
    const float* bn_m   = (const float*)d_in[5];
    const float* bn_v   = (const float*)d_in[6];
    const float* wq1    = (const float*)d_in[7];
    const float* wk1    = (const float*)d_in[8];
    const float* wv1    = (const float*)d_in[9];
    const float* lnA1_g = (const float*)d_in[10];
    const float* lnA1_b = (const float*)d_in[11];
    const float* wq2    = (const float*)d_in[12];
    const float* wk2    = (const float*)d_in[13];
    const float* wv2    = (const float*)d_in[14];
    const float* lnA2_g = (const float*)d_in[15];
    const float* lnA2_b = (const float*)d_in[16];
    const float* ln2_g  = (const float*)d_in[17];
    const float* ln2_b  = (const float*)d_in[18];
    const float* out_w  = (const float*)d_in[19];
    const float* out_b  = (const float*)d_in[20];
    float* out = (float*)d_out;

    const size_t peN = (size_t)SEQ * EMB;
    const size_t wN  = (size_t)EMB * EMB;

    int chunk = B_TOT;
    while (chunk > 1) {
        size_t M    = (size_t)chunk * SEQ;
        size_t Mpad = (M + 127) / 128 * 128;
        size_t need = peN * 4 + 6 * wN * 2 + (Mpad + 4 * M) * EMB * 2;
        if (need <= ws_size) break;
        chunk >>= 1;
    }
    size_t M    = (size_t)chunk * SEQ;
    size_t Mpad = (M + 127) / 128 * 128;

    float*          pe = (float*)d_ws;
    __hip_bfloat16* Wb = (__hip_bfloat16*)(pe + peN);
    __hip_bfloat16* Xb = Wb + 6 * wN;
    __hip_bfloat16* Ob = Xb + Mpad * EMB;
    __hip_bfloat16* Qb = Ob + M * EMB;
    __hip_bfloat16* Kb = Qb + M * EMB;
    __hip_bfloat16* Vb = Kb + M * EMB;

    pe_kernel<<<(SEQ * EMB + 255) / 256, 256, 0, stream>>>(pe);
    {
        dim3 cg((unsigned)(wN / 1024), 6);
        cvt6_kernel<<<cg, 256, 0, stream>>>(wq1, wk1, wv1, wq2, wk2, wv2, Wb, (int)wN);
    }

    for (int b0 = 0; b0 < B_TOT; b0 += chunk) {
        int Bc = chunk;
        int Mi = Bc * SEQ;
        dim3 ggrid((unsigned)(Mpad / 128), 6);

        embed_kernel<<<Bc * SEQ, 256, 0, stream>>>(
            x + (size_t)b0 * LIN, conv_w, conv_b, bn_g, bn_b, bn_m, bn_v, pe, Xb);

        // --- attention block 1 ---
        gemm_qkv_mfma<<<ggrid, 256, 0, stream>>>(Xb, Wb, Qb, Kb, Vb, Mi);
        attn_mfma_kernel<<<Bc * HEADS, 256, 0, stream>>>(Qb, Kb, Vb, Ob);
        ln_pe4_kernel<<<(Mi + 3) / 4, 256, 0, stream>>>(Ob, lnA1_g, lnA1_b, pe, Xb, Mi);

        // --- attention block 2 ---
        gemm_qkv_mfma<<<ggrid, 256, 0, stream>>>(Xb, Wb + 3 * wN, Qb, Kb, Vb, Mi);
        attn_mfma_kernel<<<Bc * HEADS, 256, 0, stream>>>(Qb, Kb, Vb, Ob);
        lnfc_kernel<<<Bc, 256, 0, stream>>>(Ob, lnA2_g, lnA2_b, ln2_g, ln2_b,
                                            out_w, out_b, out + (size_t)b0 * 10);
    }
}